// Round 1
// baseline (789.367 us; speedup 1.0000x reference)
//
#include <hip/hip_runtime.h>

typedef unsigned int u32;
typedef unsigned short u16;

__device__ __forceinline__ float bf2f(u32 lo16) {
    return __uint_as_float(lo16 << 16);
}
__device__ __forceinline__ u16 f2bf(float f) {
    u32 u = __float_as_uint(f);
    u32 r = (u + 0x7FFFu + ((u >> 16) & 1u)) >> 16;
    return (u16)r;
}

// ---------------- K2: H matmuls: H0=x@Won H1=x2@Won H2=x@Wtg H3=x2@Wtg (bf16 out)
__global__ __launch_bounds__(256) void k_h4(
    const float* __restrict__ x, const float* __restrict__ perb,
    const float* __restrict__ Won, const float* __restrict__ Wtg,
    u32* __restrict__ H32, int N)
{
    __shared__ float lx[32][128];
    __shared__ float l2[32][128];
    const int r0 = blockIdx.x * 32;
    for (int i = threadIdx.x; i < 32 * 128; i += 256) {
        int r = i >> 7, c = i & 127;
        int gr = r0 + r;
        float xv = 0.f, pv = 0.f;
        if (gr < N) { xv = x[(size_t)gr * 128 + c]; pv = perb[(size_t)gr * 128 + c]; }
        lx[r][c] = xv;
        l2[r][c] = xv + pv;
    }
    __syncthreads();
    const int wave = threadIdx.x >> 6;
    const int lane = threadIdx.x & 63;
    const int rr = wave * 8;
    float2 a0[8], a1[8], a2[8], a3[8];
#pragma unroll
    for (int r = 0; r < 8; r++) {
        a0[r] = make_float2(0.f, 0.f); a1[r] = make_float2(0.f, 0.f);
        a2[r] = make_float2(0.f, 0.f); a3[r] = make_float2(0.f, 0.f);
    }
    const float2* wonp = (const float2*)Won;
    const float2* wtgp = (const float2*)Wtg;
#pragma unroll 2
    for (int k = 0; k < 128; k++) {
        float2 wo = wonp[k * 64 + lane];
        float2 wt = wtgp[k * 64 + lane];
#pragma unroll
        for (int r = 0; r < 8; r++) {
            float xk = lx[rr + r][k];
            float yk = l2[rr + r][k];
            a0[r].x = fmaf(xk, wo.x, a0[r].x); a0[r].y = fmaf(xk, wo.y, a0[r].y);
            a1[r].x = fmaf(yk, wo.x, a1[r].x); a1[r].y = fmaf(yk, wo.y, a1[r].y);
            a2[r].x = fmaf(xk, wt.x, a2[r].x); a2[r].y = fmaf(xk, wt.y, a2[r].y);
            a3[r].x = fmaf(yk, wt.x, a3[r].x); a3[r].y = fmaf(yk, wt.y, a3[r].y);
        }
    }
    const size_t ND2 = (size_t)N * 64;
#pragma unroll
    for (int r = 0; r < 8; r++) {
        int gr = r0 + rr + r;
        if (gr < N) {
            size_t b = (size_t)gr * 64 + lane;
            H32[0 * ND2 + b] = (u32)f2bf(a0[r].x) | ((u32)f2bf(a0[r].y) << 16);
            H32[1 * ND2 + b] = (u32)f2bf(a1[r].x) | ((u32)f2bf(a1[r].y) << 16);
            H32[2 * ND2 + b] = (u32)f2bf(a2[r].x) | ((u32)f2bf(a2[r].y) << 16);
            H32[3 * ND2 + b] = (u32)f2bf(a3[r].x) | ((u32)f2bf(a3[r].y) << 16);
        }
    }
}

// ---------------- CSR build
__global__ void k_count(const int* __restrict__ row, int* __restrict__ cnt, int E) {
    int e = blockIdx.x * blockDim.x + threadIdx.x;
    if (e < E) atomicAdd(&cnt[row[e]], 1);
}

__global__ __launch_bounds__(1024) void k_scan(const int* __restrict__ cnt, int* __restrict__ off, int N, int E) {
    __shared__ int ts[1024];
    int t = threadIdx.x;
    int CH = (N + 1023) >> 10;
    int lo = t * CH;
    int hi = lo + CH; if (hi > N) hi = N; if (lo > N) lo = N;
    int s = 0;
    for (int i = lo; i < hi; i++) s += cnt[i];
    ts[t] = s;
    __syncthreads();
    for (int d = 1; d < 1024; d <<= 1) {
        int add = (t >= d) ? ts[t - d] : 0;
        __syncthreads();
        ts[t] += add;
        __syncthreads();
    }
    int base = (t == 0) ? 0 : ts[t - 1];
    for (int i = lo; i < hi; i++) { off[i] = base; base += cnt[i]; }
    if (t == 0) off[N] = E;
}

__global__ void k_scatter(const int* __restrict__ row, const int* __restrict__ col, const float* __restrict__ w,
                          const int* __restrict__ off, int* __restrict__ fill,
                          int* __restrict__ ccol, float* __restrict__ cw, int E) {
    int e = blockIdx.x * blockDim.x + threadIdx.x;
    if (e < E) {
        int r = row[e];
        int pos = off[r] + atomicAdd(&fill[r], 1);
        ccol[pos] = col[e];
        cw[pos] = w[e];
    }
}

// ---------------- K4: gather aggregation, wave per node, all 4 matrices. agg stored fp32.
__global__ __launch_bounds__(256) void k_agg(
    const u32* __restrict__ H32, const int* __restrict__ off,
    const int* __restrict__ ccol, const float* __restrict__ cw,
    float* __restrict__ AG, int N)
{
    int wave = threadIdx.x >> 6;
    int lane = threadIdx.x & 63;
    int node = blockIdx.x * 4 + wave;
    if (node >= N) return;
    const size_t ND2 = (size_t)N * 64;
    const size_t ND = (size_t)N * 128;
    int o0 = off[node], o1 = off[node + 1];
    float a00=0,a01=0,a10=0,a11=0,a20=0,a21=0,a30=0,a31=0;
    for (int e = o0; e < o1; e++) {
        int c = ccol[e];
        float w = cw[e];
        size_t b = (size_t)c * 64 + lane;
        u32 u0 = H32[b];
        u32 u1 = H32[ND2 + b];
        u32 u2 = H32[2 * ND2 + b];
        u32 u3 = H32[3 * ND2 + b];
        a00 = fmaf(w, bf2f(u0 & 0xffffu), a00); a01 = fmaf(w, bf2f(u0 >> 16), a01);
        a10 = fmaf(w, bf2f(u1 & 0xffffu), a10); a11 = fmaf(w, bf2f(u1 >> 16), a11);
        a20 = fmaf(w, bf2f(u2 & 0xffffu), a20); a21 = fmaf(w, bf2f(u2 >> 16), a21);
        a30 = fmaf(w, bf2f(u3 & 0xffffu), a30); a31 = fmaf(w, bf2f(u3 >> 16), a31);
    }
    size_t b2i = (size_t)node * 64 + lane;
    ((float2*)(AG))[b2i]          = make_float2(a00, a01);
    ((float2*)(AG + ND))[b2i]     = make_float2(a10, a11);
    ((float2*)(AG + 2 * ND))[b2i] = make_float2(a20, a21);
    ((float2*)(AG + 3 * ND))[b2i] = make_float2(a30, a31);
}

// ---------------- c1 = b_on @ W1 + b1
__global__ __launch_bounds__(128) void k_c1(const float* __restrict__ b_on, const float* __restrict__ W1,
                                            const float* __restrict__ b1, float* __restrict__ c1) {
    int d = threadIdx.x;
    float s = b1[d];
    for (int k = 0; k < 128; k++) s = fmaf(b_on[k], W1[k * 128 + d], s);
    c1[d] = s;
}

// ---------------- K5: h1x = agg0@W1 + c1 ; h1y = agg1@W1 + c1  (fp32 out)
__global__ __launch_bounds__(256) void k_h1(
    const float* __restrict__ AG, const float* __restrict__ W1, const float* __restrict__ c1,
    float* __restrict__ h1x, float* __restrict__ h1y, int N)
{
    __shared__ float ax[32][128];
    __shared__ float ay[32][128];
    const int r0 = blockIdx.x * 32;
    const size_t ND = (size_t)N * 128;
    for (int i = threadIdx.x; i < 32 * 64; i += 256) {
        int r = i >> 6, j = i & 63;
        int gr = r0 + r;
        float2 v0 = make_float2(0.f, 0.f), v1 = make_float2(0.f, 0.f);
        if (gr < N) {
            size_t b = (size_t)gr * 64 + j;
            v0 = ((const float2*)AG)[b];          // agg0 -> online_x
            v1 = ((const float2*)(AG + ND))[b];   // agg1 -> online_y
        }
        ax[r][2 * j] = v0.x; ax[r][2 * j + 1] = v0.y;
        ay[r][2 * j] = v1.x; ay[r][2 * j + 1] = v1.y;
    }
    __syncthreads();
    const int wave = threadIdx.x >> 6, lane = threadIdx.x & 63, rr = wave * 8;
    float2 axc[8], ayc[8];
#pragma unroll
    for (int r = 0; r < 8; r++) { axc[r] = make_float2(0.f, 0.f); ayc[r] = make_float2(0.f, 0.f); }
    const float2* w1p = (const float2*)W1;
#pragma unroll 2
    for (int k = 0; k < 128; k++) {
        float2 wv = w1p[k * 64 + lane];
#pragma unroll
        for (int r = 0; r < 8; r++) {
            float xv = ax[rr + r][k], yv = ay[rr + r][k];
            axc[r].x = fmaf(xv, wv.x, axc[r].x); axc[r].y = fmaf(xv, wv.y, axc[r].y);
            ayc[r].x = fmaf(yv, wv.x, ayc[r].x); ayc[r].y = fmaf(yv, wv.y, ayc[r].y);
        }
    }
    float2 cv = ((const float2*)c1)[lane];
#pragma unroll
    for (int r = 0; r < 8; r++) {
        int gr = r0 + rr + r;
        if (gr < N) {
            ((float2*)h1x)[(size_t)gr * 64 + lane] = make_float2(axc[r].x + cv.x, axc[r].y + cv.y);
            ((float2*)h1y)[(size_t)gr * 64 + lane] = make_float2(ayc[r].x + cv.x, ayc[r].y + cv.y);
        }
    }
}

// ---------------- K6: BN stats (sum, sumsq per column, both paths)
__global__ __launch_bounds__(256) void k_bnstats(
    const float* __restrict__ h1x, const float* __restrict__ h1y,
    float* __restrict__ sums, int N)
{
    int col = threadIdx.x & 127, half = threadIdx.x >> 7;
    int nb = gridDim.x;
    int rows_per = (N + nb - 1) / nb;
    int r0 = blockIdx.x * rows_per, r1 = r0 + rows_per;
    if (r1 > N) r1 = N;
    float s1x = 0.f, s2x = 0.f, s1y = 0.f, s2y = 0.f;
    for (int r = r0 + half; r < r1; r += 2) {
        float v = h1x[(size_t)r * 128 + col];
        s1x += v; s2x = fmaf(v, v, s2x);
        float u = h1y[(size_t)r * 128 + col];
        s1y += u; s2y = fmaf(u, u, s2y);
    }
    __shared__ float red[4][256];
    red[0][threadIdx.x] = s1x; red[1][threadIdx.x] = s2x;
    red[2][threadIdx.x] = s1y; red[3][threadIdx.x] = s2y;
    __syncthreads();
    if (half == 0) {
        atomicAdd(&sums[col],       red[0][col] + red[0][col + 128]);
        atomicAdd(&sums[128 + col], red[1][col] + red[1][col + 128]);
        atomicAdd(&sums[256 + col], red[2][col] + red[2][col + 128]);
        atomicAdd(&sums[384 + col], red[3][col] + red[3][col + 128]);
    }
}

__global__ __launch_bounds__(128) void k_bnfin(
    const float* __restrict__ sums, const float* __restrict__ g, const float* __restrict__ beta,
    float* __restrict__ bnp, int N)
{
    int d = threadIdx.x;
    float inv = 1.0f / (float)N;
    float mux = sums[d] * inv;
    float varx = sums[128 + d] * inv - mux * mux;
    float isx = rsqrtf(varx + 1e-5f);
    bnp[d]       = g[d] * isx;
    bnp[128 + d] = beta[d] - mux * g[d] * isx;
    float muy = sums[256 + d] * inv;
    float vary = sums[384 + d] * inv - muy * muy;
    float isy = rsqrtf(vary + 1e-5f);
    bnp[256 + d] = g[d] * isy;
    bnp[384 + d] = beta[d] - muy * g[d] * isy;
}

// ---------------- K7: BN apply + PReLU + @W2 + b2 + cosine loss vs targets
__global__ __launch_bounds__(256) void k_loss(
    const float* __restrict__ h1x, const float* __restrict__ h1y,
    const float* __restrict__ bnp, const float* __restrict__ prelu_a,
    const float* __restrict__ W2, const float* __restrict__ b2,
    const float* __restrict__ AG, const float* __restrict__ b_tg,
    float* __restrict__ loss, int N)
{
    __shared__ float hbx[4][8][128];
    __shared__ float hby[4][8][128];
    const int wave = threadIdx.x >> 6, lane = threadIdx.x & 63;
    const int r0 = (blockIdx.x * 4 + wave) * 8;
    const size_t ND = (size_t)N * 128;
    float2 scx = ((const float2*)bnp)[lane];
    float2 shx = ((const float2*)(bnp + 128))[lane];
    float2 scy = ((const float2*)(bnp + 256))[lane];
    float2 shy = ((const float2*)(bnp + 384))[lane];
    float aslope = prelu_a[0];
#pragma unroll
    for (int r = 0; r < 8; r++) {
        int gr = r0 + r;
        float2 hx = make_float2(0.f, 0.f), hy = make_float2(0.f, 0.f);
        if (gr < N) {
            hx = ((const float2*)h1x)[(size_t)gr * 64 + lane];
            hy = ((const float2*)h1y)[(size_t)gr * 64 + lane];
        }
        float bx0 = hx.x * scx.x + shx.x; bx0 = bx0 > 0.f ? bx0 : aslope * bx0;
        float bx1 = hx.y * scx.y + shx.y; bx1 = bx1 > 0.f ? bx1 : aslope * bx1;
        float by0 = hy.x * scy.x + shy.x; by0 = by0 > 0.f ? by0 : aslope * by0;
        float by1 = hy.y * scy.y + shy.y; by1 = by1 > 0.f ? by1 : aslope * by1;
        hbx[wave][r][2 * lane] = bx0; hbx[wave][r][2 * lane + 1] = bx1;
        hby[wave][r][2 * lane] = by0; hby[wave][r][2 * lane + 1] = by1;
    }
    __syncthreads();
    float2 px[8], py[8];
#pragma unroll
    for (int r = 0; r < 8; r++) { px[r] = make_float2(0.f, 0.f); py[r] = make_float2(0.f, 0.f); }
    const float2* w2p = (const float2*)W2;
#pragma unroll 2
    for (int k = 0; k < 128; k++) {
        float2 wv = w2p[k * 64 + lane];
#pragma unroll
        for (int r = 0; r < 8; r++) {
            float xv = hbx[wave][r][k], yv = hby[wave][r][k];
            px[r].x = fmaf(xv, wv.x, px[r].x); px[r].y = fmaf(xv, wv.y, px[r].y);
            py[r].x = fmaf(yv, wv.x, py[r].x); py[r].y = fmaf(yv, wv.y, py[r].y);
        }
    }
    float2 b2v = ((const float2*)b2)[lane];
    float2 btv = ((const float2*)b_tg)[lane];
    float lsum = 0.f;
#pragma unroll 1
    for (int r = 0; r < 8; r++) {
        int gr = r0 + r;
        if (gr >= N) continue;
        size_t b = (size_t)gr * 64 + lane;
        float2 t3 = ((const float2*)(AG + 3 * ND))[b];  // target_x = agg3 + b_tg
        float2 t2 = ((const float2*)(AG + 2 * ND))[b];  // target_y = agg2 + b_tg
        float tx0 = t3.x + btv.x, tx1 = t3.y + btv.y;
        float ty0 = t2.x + btv.x, ty1 = t2.y + btv.y;
        float pxx = px[r].x + b2v.x, pxy = px[r].y + b2v.y;
        float pyx = py[r].x + b2v.x, pyy = py[r].y + b2v.y;
        float pp = pxx * pxx + pxy * pxy;
        float tt = tx0 * tx0 + tx1 * tx1;
        float pt = pxx * tx0 + pxy * tx1;
        float qq = pyx * pyx + pyy * pyy;
        float ss = ty0 * ty0 + ty1 * ty1;
        float qs = pyx * ty0 + pyy * ty1;
#pragma unroll
        for (int m = 1; m < 64; m <<= 1) {
            pp += __shfl_xor(pp, m);
            tt += __shfl_xor(tt, m);
            pt += __shfl_xor(pt, m);
            qq += __shfl_xor(qq, m);
            ss += __shfl_xor(ss, m);
            qs += __shfl_xor(qs, m);
        }
        float cx = pt / (fmaxf(sqrtf(pp), 1e-12f) * fmaxf(sqrtf(tt), 1e-12f));
        float cy = qs / (fmaxf(sqrtf(qq), 1e-12f) * fmaxf(sqrtf(ss), 1e-12f));
        lsum += (2.f - 2.f * cx) + (2.f - 2.f * cy);
    }
    if (lane == 0 && r0 < N) atomicAdd(loss, lsum);
}

// ---------------- K8: embed = x + perb + agg1 + b_on ; plus loss scalar
__global__ __launch_bounds__(256) void k_embed(
    const float* __restrict__ x, const float* __restrict__ perb,
    const float* __restrict__ AG, const float* __restrict__ b_on,
    const float* __restrict__ loss, float* __restrict__ out, int N)
{
    const size_t ND2 = (size_t)N * 64;
    const size_t ND = (size_t)N * 128;
    size_t i = (size_t)blockIdx.x * blockDim.x + threadIdx.x;
    size_t stride = (size_t)gridDim.x * blockDim.x;
    for (; i < ND2; i += stride) {
        int j = (int)(i & 63);
        float2 ag = ((const float2*)(AG + ND))[i];   // agg1
        float2 xv = ((const float2*)x)[i];
        float2 pv = ((const float2*)perb)[i];
        float2 bo = ((const float2*)b_on)[j];
        float2 o;
        o.x = xv.x + pv.x + ag.x + bo.x;
        o.y = xv.y + pv.y + ag.y + bo.y;
        ((float2*)out)[i] = o;
    }
    if (blockIdx.x == 0 && threadIdx.x == 0) {
        out[ND] = loss[0] * (1.0f / (float)N);
    }
}

extern "C" void kernel_launch(void* const* d_in, const int* in_sizes, int n_in,
                              void* d_out, int out_size, void* d_ws, size_t ws_size,
                              hipStream_t stream)
{
    const float* x    = (const float*)d_in[0];
    const float* perb = (const float*)d_in[1];
    const int*   erow = (const int*)d_in[2];
    const int*   ecol = (const int*)d_in[3];
    const float* ew   = (const float*)d_in[4];
    const float* Won  = (const float*)d_in[5];
    const float* bon  = (const float*)d_in[6];
    const float* Wtg  = (const float*)d_in[7];
    const float* btg  = (const float*)d_in[8];
    const float* W1   = (const float*)d_in[9];
    const float* b1   = (const float*)d_in[10];
    const float* bng  = (const float*)d_in[11];
    const float* bnb  = (const float*)d_in[12];
    const float* pra  = (const float*)d_in[13];
    const float* W2   = (const float*)d_in[14];
    const float* b2   = (const float*)d_in[15];
    float* out = (float*)d_out;

    const int N = in_sizes[0] / 128;
    const int E = in_sizes[2];
    const size_t ND = (size_t)N * 128;

    char* ws = (char*)d_ws;
    const size_t szH  = 4 * ND * 2;   // 4 bf16 matrices
    const size_t szAG = 4 * ND * 4;   // 4 fp32 agg matrices
    u32*   H32 = (u32*)ws;
    float* AG  = (float*)(ws + szH);
    float* h1x = (float*)ws;                 // reuse H region after aggregation
    float* h1y = (float*)(ws + ND * 4);

    char* p = ws + szH + szAG;
    const size_t szcnt = (((size_t)(N + 16) * 4) + 63) & ~(size_t)63;
    int* cnt  = (int*)p;      p += szcnt;
    int* fill = (int*)p;      p += szcnt;
    float* sums = (float*)p;  p += 2048;
    float* loss = (float*)p;  p += 64;
    size_t zero_bytes = (size_t)(p - (char*)cnt);
    int* off  = (int*)p;      p += szcnt;
    int* ccol = (int*)p;      p += (((size_t)E * 4) + 63) & ~(size_t)63;
    float* cw = (float*)p;    p += (((size_t)E * 4) + 63) & ~(size_t)63;
    float* c1 = (float*)p;    p += 512;
    float* bnp = (float*)p;   p += 2048;

    hipMemsetAsync(cnt, 0, zero_bytes, stream);

    k_c1<<<1, 128, 0, stream>>>(bon, W1, b1, c1);
    const int nb32 = (N + 31) / 32;
    k_h4<<<nb32, 256, 0, stream>>>(x, perb, Won, Wtg, H32, N);
    k_count<<<(E + 255) / 256, 256, 0, stream>>>(erow, cnt, E);
    k_scan<<<1, 1024, 0, stream>>>(cnt, off, N, E);
    k_scatter<<<(E + 255) / 256, 256, 0, stream>>>(erow, ecol, ew, off, fill, ccol, cw, E);
    k_agg<<<(N + 3) / 4, 256, 0, stream>>>(H32, off, ccol, cw, AG, N);
    k_h1<<<nb32, 256, 0, stream>>>(AG, W1, c1, h1x, h1y, N);
    k_bnstats<<<256, 256, 0, stream>>>(h1x, h1y, sums, N);
    k_bnfin<<<1, 128, 0, stream>>>(sums, bng, bnb, bnp, N);
    k_loss<<<nb32, 256, 0, stream>>>(h1x, h1y, bnp, pra, W2, b2, AG, btg, loss, N);
    k_embed<<<1024, 256, 0, stream>>>(x, perb, AG, bon, loss, out, N);
}

// Round 2
// 569.774 us; speedup vs baseline: 1.3854x; 1.3854x over previous
//
#include <hip/hip_runtime.h>

typedef unsigned int u32;
typedef unsigned short u16;
typedef __attribute__((ext_vector_type(8))) short short8;
typedef __attribute__((ext_vector_type(4))) float floatx4;

union F8 { uint4 u4; short8 s8; };

__device__ __forceinline__ float bf2f(u32 lo16) { return __uint_as_float(lo16 << 16); }
__device__ __forceinline__ u16 f2bf(float f) {
    u32 u = __float_as_uint(f);
    return (u16)((u + 0x7FFFu + ((u >> 16) & 1u)) >> 16);
}
__device__ __forceinline__ u32 pack2(float a, float b) {
    return (u32)f2bf(a) | ((u32)f2bf(b) << 16);
}

// ---------------- W fragment prep: Wfrag[mat][ct][ks][lane][8] bf16
// A-operand layout for mfma_f32_16x16x32_bf16 (W^T as A):
//   A[m'=lane&15][k=(lane>>4)*8+j], m' = W-col n = ct*16+(lane&15), k = ks*32+...
__global__ __launch_bounds__(256) void k_wfrag(
    const float* __restrict__ Won, const float* __restrict__ Wtg,
    const float* __restrict__ W1, const float* __restrict__ W2,
    u16* __restrict__ Wfrag)
{
    int mat = blockIdx.x;
    const float* W = mat == 0 ? Won : (mat == 1 ? Wtg : (mat == 2 ? W1 : W2));
    uint4* out = (uint4*)(Wfrag + (size_t)mat * 16384);
    for (int s = threadIdx.x; s < 2048; s += 256) {
        int ct = s >> 8, ks = (s >> 6) & 3, lane = s & 63;
        int n = ct * 16 + (lane & 15);
        int k0 = ks * 32 + (lane >> 4) * 8;
        u32 p[4];
#pragma unroll
        for (int jj = 0; jj < 4; jj++) {
            float a = W[(size_t)(k0 + 2 * jj) * 128 + n];
            float b = W[(size_t)(k0 + 2 * jj + 1) * 128 + n];
            p[jj] = pack2(a, b);
        }
        out[s] = make_uint4(p[0], p[1], p[2], p[3]);
    }
}

// ---------------- c1 = b_on @ W1 + b1
__global__ __launch_bounds__(128) void k_c1(const float* __restrict__ b_on, const float* __restrict__ W1,
                                            const float* __restrict__ b1, float* __restrict__ c1) {
    int d = threadIdx.x;
    float s = b1[d];
    for (int k = 0; k < 128; k++) s = fmaf(b_on[k], W1[k * 128 + d], s);
    c1[d] = s;
}

// ---------------- K_h4: H0=x@Won H1=x2@Won H2=x@Wtg H3=x2@Wtg, interleaved [row][4][128] bf16
__global__ __launch_bounds__(256) void k_h4(
    const float* __restrict__ x, const float* __restrict__ perb,
    const u16* __restrict__ Wfrag, u16* __restrict__ H, int N)
{
    const int wave = threadIdx.x >> 6, lane = threadIdx.x & 63;
    const int m = lane & 15, q = lane >> 4;
    const int grow = blockIdx.x * 64 + wave * 16 + m;
    const int rc = grow < N ? grow : N - 1;
    const bool valid = grow < N;
    const float* xr = x + (size_t)rc * 128;
    const float* pr = perb + (size_t)rc * 128;
    short8 fx[4], fx2[4];
#pragma unroll
    for (int ks = 0; ks < 4; ks++) {
        int c0 = ks * 32 + q * 8;
        float4 a = *(const float4*)(xr + c0);
        float4 b = *(const float4*)(xr + c0 + 4);
        float4 pa = *(const float4*)(pr + c0);
        float4 pb = *(const float4*)(pr + c0 + 4);
        F8 t;
        t.u4 = make_uint4(pack2(a.x, a.y), pack2(a.z, a.w), pack2(b.x, b.y), pack2(b.z, b.w));
        fx[ks] = t.s8;
        t.u4 = make_uint4(pack2(a.x + pa.x, a.y + pa.y), pack2(a.z + pa.z, a.w + pa.w),
                          pack2(b.x + pb.x, b.y + pb.y), pack2(b.z + pb.z, b.w + pb.w));
        fx2[ks] = t.s8;
    }
    const uint4* wf = (const uint4*)Wfrag;
#pragma unroll 1
    for (int mat = 0; mat < 2; mat++) {
#pragma unroll 2
        for (int ct = 0; ct < 8; ct++) {
            floatx4 acc0 = {0.f, 0.f, 0.f, 0.f}, acc1 = {0.f, 0.f, 0.f, 0.f};
#pragma unroll
            for (int ks = 0; ks < 4; ks++) {
                F8 w; w.u4 = wf[((mat * 8 + ct) * 4 + ks) * 64 + lane];
                acc0 = __builtin_amdgcn_mfma_f32_16x16x32_bf16(w.s8, fx[ks], acc0, 0, 0, 0);
                acc1 = __builtin_amdgcn_mfma_f32_16x16x32_bf16(w.s8, fx2[ks], acc1, 0, 0, 0);
            }
            if (valid) {
                int c0 = ct * 16 + q * 4;
                u16* hp = H + ((size_t)grow * 4 + mat * 2) * 128 + c0;
                *(uint2*)hp         = make_uint2(pack2(acc0[0], acc0[1]), pack2(acc0[2], acc0[3]));
                *(uint2*)(hp + 128) = make_uint2(pack2(acc1[0], acc1[1]), pack2(acc1[2], acc1[3]));
            }
        }
    }
}

// ---------------- CSR build
__global__ void k_count(const int* __restrict__ row, int* __restrict__ cnt, int E) {
    int e = blockIdx.x * blockDim.x + threadIdx.x;
    if (e < E) atomicAdd(&cnt[row[e]], 1);
}

__global__ __launch_bounds__(1024) void k_scan(const int* __restrict__ cnt, int* __restrict__ off, int N, int E) {
    __shared__ int ts[1024];
    int t = threadIdx.x;
    int CH = (N + 1023) >> 10;
    int lo = t * CH;
    int hi = lo + CH; if (hi > N) hi = N; if (lo > N) lo = N;
    int s = 0;
    for (int i = lo; i < hi; i++) s += cnt[i];
    ts[t] = s;
    __syncthreads();
    for (int d = 1; d < 1024; d <<= 1) {
        int add = (t >= d) ? ts[t - d] : 0;
        __syncthreads();
        ts[t] += add;
        __syncthreads();
    }
    int base = (t == 0) ? 0 : ts[t - 1];
    for (int i = lo; i < hi; i++) { off[i] = base; base += cnt[i]; }
    if (t == 0) off[N] = E;
}

__global__ void k_scatter(const int* __restrict__ row, const int* __restrict__ col, const float* __restrict__ w,
                          const int* __restrict__ off, int* __restrict__ fill,
                          int* __restrict__ ccol, float* __restrict__ cw, int E) {
    int e = blockIdx.x * blockDim.x + threadIdx.x;
    if (e < E) {
        int r = row[e];
        int pos = off[r] + atomicAdd(&fill[r], 1);
        ccol[pos] = col[e];
        cw[pos] = w[e];
    }
}

// ---------------- K_agg: wave per node, one 1KB coalesced gather per edge (all 4 mats)
__global__ __launch_bounds__(256) void k_agg(
    const u16* __restrict__ H, const int* __restrict__ off,
    const int* __restrict__ ccol, const float* __restrict__ cw,
    u16* __restrict__ AGh, int N)
{
    int wave = threadIdx.x >> 6, lane = threadIdx.x & 63;
    int node = blockIdx.x * 4 + wave;
    if (node >= N) return;
    int o0 = off[node], o1 = off[node + 1];
    float acc[8] = {0.f, 0.f, 0.f, 0.f, 0.f, 0.f, 0.f, 0.f};
#pragma unroll 2
    for (int e = o0; e < o1; e++) {
        int c = ccol[e];
        float w = cw[e];
        uint4 v = ((const uint4*)(H + (size_t)c * 512))[lane];
        acc[0] = fmaf(w, bf2f(v.x & 0xffffu), acc[0]);
        acc[1] = fmaf(w, bf2f(v.x >> 16), acc[1]);
        acc[2] = fmaf(w, bf2f(v.y & 0xffffu), acc[2]);
        acc[3] = fmaf(w, bf2f(v.y >> 16), acc[3]);
        acc[4] = fmaf(w, bf2f(v.z & 0xffffu), acc[4]);
        acc[5] = fmaf(w, bf2f(v.z >> 16), acc[5]);
        acc[6] = fmaf(w, bf2f(v.w & 0xffffu), acc[6]);
        acc[7] = fmaf(w, bf2f(v.w >> 16), acc[7]);
    }
    uint4 o;
    o.x = pack2(acc[0], acc[1]); o.y = pack2(acc[2], acc[3]);
    o.z = pack2(acc[4], acc[5]); o.w = pack2(acc[6], acc[7]);
    ((uint4*)(AGh + (size_t)node * 512))[lane] = o;
}

// ---------------- K_h1: h1x = agg0@W1+c1, h1y = agg1@W1+c1 (bf16 out, row-major)
__global__ __launch_bounds__(256) void k_h1(
    const u16* __restrict__ AGh, const u16* __restrict__ Wfrag, const float* __restrict__ c1,
    u16* __restrict__ h1x, u16* __restrict__ h1y, int N)
{
    const int wave = threadIdx.x >> 6, lane = threadIdx.x & 63;
    const int m = lane & 15, q = lane >> 4;
    const int grow = blockIdx.x * 64 + wave * 16 + m;
    const int rc = grow < N ? grow : N - 1;
    const bool valid = grow < N;
    const u16* ar = AGh + (size_t)rc * 512;
    short8 fa[4], fb[4];
#pragma unroll
    for (int ks = 0; ks < 4; ks++) {
        int c0 = ks * 32 + q * 8;
        F8 t;
        t.u4 = *(const uint4*)(ar + c0);       fa[ks] = t.s8;   // agg0 (online_x)
        t.u4 = *(const uint4*)(ar + 128 + c0); fb[ks] = t.s8;   // agg1 (online_y)
    }
    const uint4* wf = (const uint4*)(Wfrag + 2 * 16384);
#pragma unroll 2
    for (int ct = 0; ct < 8; ct++) {
        floatx4 ax = {0.f, 0.f, 0.f, 0.f}, ay = {0.f, 0.f, 0.f, 0.f};
#pragma unroll
        for (int ks = 0; ks < 4; ks++) {
            F8 w; w.u4 = wf[(ct * 4 + ks) * 64 + lane];
            ax = __builtin_amdgcn_mfma_f32_16x16x32_bf16(w.s8, fa[ks], ax, 0, 0, 0);
            ay = __builtin_amdgcn_mfma_f32_16x16x32_bf16(w.s8, fb[ks], ay, 0, 0, 0);
        }
        if (valid) {
            int c0 = ct * 16 + q * 4;
            float4 cv = *(const float4*)(c1 + c0);
            u16* px = h1x + (size_t)grow * 128 + c0;
            u16* py = h1y + (size_t)grow * 128 + c0;
            *(uint2*)px = make_uint2(pack2(ax[0] + cv.x, ax[1] + cv.y), pack2(ax[2] + cv.z, ax[3] + cv.w));
            *(uint2*)py = make_uint2(pack2(ay[0] + cv.x, ay[1] + cv.y), pack2(ay[2] + cv.z, ay[3] + cv.w));
        }
    }
}

// ---------------- BN stats over bf16 h1
__global__ __launch_bounds__(256) void k_bnstats(
    const u32* __restrict__ h1x32, const u32* __restrict__ h1y32,
    float* __restrict__ sums, int N)
{
    int c2 = threadIdx.x & 63, g = threadIdx.x >> 6;
    int per = (N + gridDim.x - 1) / gridDim.x;
    int r0 = blockIdx.x * per, r1 = r0 + per;
    if (r1 > N) r1 = N;
    float s[8] = {0.f, 0.f, 0.f, 0.f, 0.f, 0.f, 0.f, 0.f};
    for (int r = r0 + g; r < r1; r += 4) {
        u32 vx = h1x32[(size_t)r * 64 + c2];
        float lo = bf2f(vx & 0xffffu), hi = bf2f(vx >> 16);
        s[0] += lo; s[1] = fmaf(lo, lo, s[1]); s[2] += hi; s[3] = fmaf(hi, hi, s[3]);
        u32 vy = h1y32[(size_t)r * 64 + c2];
        lo = bf2f(vy & 0xffffu); hi = bf2f(vy >> 16);
        s[4] += lo; s[5] = fmaf(lo, lo, s[5]); s[6] += hi; s[7] = fmaf(hi, hi, s[7]);
    }
    __shared__ float red[256][8];
#pragma unroll
    for (int k = 0; k < 8; k++) red[threadIdx.x][k] = s[k];
    __syncthreads();
    if (g == 0) {
        float v[8];
#pragma unroll
        for (int k = 0; k < 8; k++)
            v[k] = red[c2][k] + red[c2 + 64][k] + red[c2 + 128][k] + red[c2 + 192][k];
        int c0 = 2 * c2, c1i = c0 + 1;
        atomicAdd(&sums[c0], v[0]);        atomicAdd(&sums[128 + c0], v[1]);
        atomicAdd(&sums[c1i], v[2]);       atomicAdd(&sums[128 + c1i], v[3]);
        atomicAdd(&sums[256 + c0], v[4]);  atomicAdd(&sums[384 + c0], v[5]);
        atomicAdd(&sums[256 + c1i], v[6]); atomicAdd(&sums[384 + c1i], v[7]);
    }
}

__global__ __launch_bounds__(128) void k_bnfin(
    const float* __restrict__ sums, const float* __restrict__ g, const float* __restrict__ beta,
    float* __restrict__ bnp, int N)
{
    int d = threadIdx.x;
    float inv = 1.0f / (float)N;
    float mux = sums[d] * inv;
    float varx = sums[128 + d] * inv - mux * mux;
    float isx = rsqrtf(varx + 1e-5f);
    bnp[d]       = g[d] * isx;
    bnp[128 + d] = beta[d] - mux * g[d] * isx;
    float muy = sums[256 + d] * inv;
    float vary = sums[384 + d] * inv - muy * muy;
    float isy = rsqrtf(vary + 1e-5f);
    bnp[256 + d] = g[d] * isy;
    bnp[384 + d] = beta[d] - muy * g[d] * isy;
}

// ---------------- K_loss: BN+PReLU (reg) -> @W2 via MFMA -> cosine loss (never materialize px/py)
__device__ __forceinline__ short8 bn_frag(const u16* hrow, const float* sc, const float* sh,
                                          int c0, float slope) {
    uint4 h = *(const uint4*)(hrow + c0);
    float4 s0 = *(const float4*)(sc + c0), s1 = *(const float4*)(sc + c0 + 4);
    float4 t0 = *(const float4*)(sh + c0), t1 = *(const float4*)(sh + c0 + 4);
    float v[8];
    v[0] = fmaf(bf2f(h.x & 0xffffu), s0.x, t0.x);
    v[1] = fmaf(bf2f(h.x >> 16),     s0.y, t0.y);
    v[2] = fmaf(bf2f(h.y & 0xffffu), s0.z, t0.z);
    v[3] = fmaf(bf2f(h.y >> 16),     s0.w, t0.w);
    v[4] = fmaf(bf2f(h.z & 0xffffu), s1.x, t1.x);
    v[5] = fmaf(bf2f(h.z >> 16),     s1.y, t1.y);
    v[6] = fmaf(bf2f(h.w & 0xffffu), s1.z, t1.z);
    v[7] = fmaf(bf2f(h.w >> 16),     s1.w, t1.w);
#pragma unroll
    for (int j = 0; j < 8; j++) v[j] = v[j] > 0.f ? v[j] : slope * v[j];
    F8 r;
    r.u4 = make_uint4(pack2(v[0], v[1]), pack2(v[2], v[3]), pack2(v[4], v[5]), pack2(v[6], v[7]));
    return r.s8;
}

__global__ __launch_bounds__(256) void k_loss(
    const u16* __restrict__ h1x, const u16* __restrict__ h1y,
    const u16* __restrict__ Wfrag, const float* __restrict__ bnp,
    const float* __restrict__ prelu_a, const float* __restrict__ b2,
    const u16* __restrict__ AGh, const float* __restrict__ b_tg,
    float* __restrict__ loss, int N)
{
    const int wave = threadIdx.x >> 6, lane = threadIdx.x & 63;
    const int m = lane & 15, q = lane >> 4;
    const int grow = blockIdx.x * 64 + wave * 16 + m;
    const int rc = grow < N ? grow : N - 1;
    const bool valid = grow < N;
    const float slope = prelu_a[0];
    const u16* hx = h1x + (size_t)rc * 128;
    const u16* hy = h1y + (size_t)rc * 128;
    short8 px8[4], py8[4];
#pragma unroll
    for (int ks = 0; ks < 4; ks++) {
        int c0 = ks * 32 + q * 8;
        px8[ks] = bn_frag(hx, bnp, bnp + 128, c0, slope);
        py8[ks] = bn_frag(hy, bnp + 256, bnp + 384, c0, slope);
    }
    const uint4* wf = (const uint4*)(Wfrag + 3 * 16384);
    const u16* agr = AGh + (size_t)rc * 512;
    float pp = 0.f, pt = 0.f, tt = 0.f, qq = 0.f, qs = 0.f, ss = 0.f;
#pragma unroll 2
    for (int ct = 0; ct < 8; ct++) {
        floatx4 ax = {0.f, 0.f, 0.f, 0.f}, ay = {0.f, 0.f, 0.f, 0.f};
#pragma unroll
        for (int ks = 0; ks < 4; ks++) {
            F8 w; w.u4 = wf[(ct * 4 + ks) * 64 + lane];
            ax = __builtin_amdgcn_mfma_f32_16x16x32_bf16(w.s8, px8[ks], ax, 0, 0, 0);
            ay = __builtin_amdgcn_mfma_f32_16x16x32_bf16(w.s8, py8[ks], ay, 0, 0, 0);
        }
        int c0 = ct * 16 + q * 4;
        float4 bv = *(const float4*)(b2 + c0);
        float4 tb = *(const float4*)(b_tg + c0);
        uint2 t3 = *(const uint2*)(agr + 3 * 128 + c0);  // target_x = agg3 + b_tg
        uint2 t2 = *(const uint2*)(agr + 2 * 128 + c0);  // target_y = agg2 + b_tg
        float tx[4] = { bf2f(t3.x & 0xffffu) + tb.x, bf2f(t3.x >> 16) + tb.y,
                        bf2f(t3.y & 0xffffu) + tb.z, bf2f(t3.y >> 16) + tb.w };
        float ty[4] = { bf2f(t2.x & 0xffffu) + tb.x, bf2f(t2.x >> 16) + tb.y,
                        bf2f(t2.y & 0xffffu) + tb.z, bf2f(t2.y >> 16) + tb.w };
        float pxv[4] = { ax[0] + bv.x, ax[1] + bv.y, ax[2] + bv.z, ax[3] + bv.w };
        float pyv[4] = { ay[0] + bv.x, ay[1] + bv.y, ay[2] + bv.z, ay[3] + bv.w };
#pragma unroll
        for (int j = 0; j < 4; j++) {
            pp = fmaf(pxv[j], pxv[j], pp); pt = fmaf(pxv[j], tx[j], pt); tt = fmaf(tx[j], tx[j], tt);
            qq = fmaf(pyv[j], pyv[j], qq); qs = fmaf(pyv[j], ty[j], qs); ss = fmaf(ty[j], ty[j], ss);
        }
    }
    // reduce over the 4 lanes sharing row m (quads)
    pp += __shfl_xor(pp, 16); pt += __shfl_xor(pt, 16); tt += __shfl_xor(tt, 16);
    qq += __shfl_xor(qq, 16); qs += __shfl_xor(qs, 16); ss += __shfl_xor(ss, 16);
    pp += __shfl_xor(pp, 32); pt += __shfl_xor(pt, 32); tt += __shfl_xor(tt, 32);
    qq += __shfl_xor(qq, 32); qs += __shfl_xor(qs, 32); ss += __shfl_xor(ss, 32);
    float cx = pt / (fmaxf(sqrtf(pp), 1e-12f) * fmaxf(sqrtf(tt), 1e-12f));
    float cy = qs / (fmaxf(sqrtf(qq), 1e-12f) * fmaxf(sqrtf(ss), 1e-12f));
    float lsum = valid ? (4.f - 2.f * cx - 2.f * cy) : 0.f;
    lsum += __shfl_xor(lsum, 1); lsum += __shfl_xor(lsum, 2);
    lsum += __shfl_xor(lsum, 4); lsum += __shfl_xor(lsum, 8);
    if (lane == 0) atomicAdd(loss, lsum);
}

// ---------------- K_embed: out = x + perb + agg1 + b_on ; plus loss scalar
__global__ __launch_bounds__(256) void k_embed(
    const float* __restrict__ x, const float* __restrict__ perb,
    const u32* __restrict__ AGh32, const float* __restrict__ b_on,
    const float* __restrict__ loss, float* __restrict__ out, int N)
{
    const size_t ND2 = (size_t)N * 64;
    const size_t ND = (size_t)N * 128;
    size_t i = (size_t)blockIdx.x * blockDim.x + threadIdx.x;
    size_t stride = (size_t)gridDim.x * blockDim.x;
    for (; i < ND2; i += stride) {
        int d2 = (int)(i & 63);
        size_t row = i >> 6;
        u32 v = AGh32[row * 256 + 64 + d2];   // agg1 (mat index 1)
        float2 xv = ((const float2*)x)[i];
        float2 pv = ((const float2*)perb)[i];
        float2 bo = ((const float2*)b_on)[d2];
        float2 o;
        o.x = xv.x + pv.x + bf2f(v & 0xffffu) + bo.x;
        o.y = xv.y + pv.y + bf2f(v >> 16) + bo.y;
        ((float2*)out)[i] = o;
    }
    if (blockIdx.x == 0 && threadIdx.x == 0) out[ND] = loss[0] * (1.0f / (float)N);
}

extern "C" void kernel_launch(void* const* d_in, const int* in_sizes, int n_in,
                              void* d_out, int out_size, void* d_ws, size_t ws_size,
                              hipStream_t stream)
{
    const float* x    = (const float*)d_in[0];
    const float* perb = (const float*)d_in[1];
    const int*   erow = (const int*)d_in[2];
    const int*   ecol = (const int*)d_in[3];
    const float* ew   = (const float*)d_in[4];
    const float* Won  = (const float*)d_in[5];
    const float* bon  = (const float*)d_in[6];
    const float* Wtg  = (const float*)d_in[7];
    const float* btg  = (const float*)d_in[8];
    const float* W1   = (const float*)d_in[9];
    const float* b1   = (const float*)d_in[10];
    const float* bng  = (const float*)d_in[11];
    const float* bnb  = (const float*)d_in[12];
    const float* pra  = (const float*)d_in[13];
    const float* W2   = (const float*)d_in[14];
    const float* b2   = (const float*)d_in[15];
    float* out = (float*)d_out;

    const int N = in_sizes[0] / 128;
    const int E = in_sizes[2];

    char* ws = (char*)d_ws;
    const size_t szH  = (size_t)N * 512 * 2;   // interleaved H bf16
    const size_t szAG = (size_t)N * 512 * 2;   // interleaved agg bf16
    const size_t szh1 = (size_t)N * 128 * 2;   // h1 bf16
    u16* H   = (u16*)ws;
    u16* AGh = (u16*)(ws + szH);
    u16* h1x = (u16*)(ws + szH + szAG);
    u16* h1y = (u16*)(ws + szH + szAG + szh1);

    char* p = ws + szH + szAG + 2 * szh1;
    const size_t szcnt = (((size_t)(N + 16) * 4) + 63) & ~(size_t)63;
    int* cnt  = (int*)p;      p += szcnt;
    int* fill = (int*)p;      p += szcnt;
    float* sums = (float*)p;  p += 2048;
    float* loss = (float*)p;  p += 64;
    size_t zero_bytes = (size_t)(p - (char*)cnt);
    int* off  = (int*)p;      p += szcnt;
    int* ccol = (int*)p;      p += (((size_t)E * 4) + 63) & ~(size_t)63;
    float* cw = (float*)p;    p += (((size_t)E * 4) + 63) & ~(size_t)63;
    float* c1 = (float*)p;    p += 512;
    float* bnp = (float*)p;   p += 2048;
    u16* Wfrag = (u16*)p;     p += 4 * 16384 * 2;

    hipMemsetAsync(cnt, 0, zero_bytes, stream);

    const int nb64 = (N + 63) / 64;
    k_wfrag<<<4, 256, 0, stream>>>(Won, Wtg, W1, W2, Wfrag);
    k_c1<<<1, 128, 0, stream>>>(bon, W1, b1, c1);
    k_h4<<<nb64, 256, 0, stream>>>(x, perb, Wfrag, H, N);
    k_count<<<(E + 255) / 256, 256, 0, stream>>>(erow, cnt, E);
    k_scan<<<1, 1024, 0, stream>>>(cnt, off, N, E);
    k_scatter<<<(E + 255) / 256, 256, 0, stream>>>(erow, ecol, ew, off, fill, ccol, cw, E);
    k_agg<<<(N + 3) / 4, 256, 0, stream>>>(H, off, ccol, cw, AGh, N);
    k_h1<<<nb64, 256, 0, stream>>>(AGh, Wfrag, c1, h1x, h1y, N);
    k_bnstats<<<128, 256, 0, stream>>>((const u32*)h1x, (const u32*)h1y, sums, N);
    k_bnfin<<<1, 128, 0, stream>>>(sums, bng, bnb, bnp, N);
    k_loss<<<nb64, 256, 0, stream>>>(h1x, h1y, Wfrag, bnp, pra, b2, AGh, btg, loss, N);
    k_embed<<<1024, 256, 0, stream>>>(x, perb, (const u32*)AGh, bon, loss, out, N);
}

// Round 3
// 498.536 us; speedup vs baseline: 1.5834x; 1.1429x over previous
//
#include <hip/hip_runtime.h>

typedef unsigned int u32;
typedef unsigned short u16;
typedef __attribute__((ext_vector_type(8))) short short8;
typedef __attribute__((ext_vector_type(4))) float floatx4;

union F8 { uint4 u4; short8 s8; };

__device__ __forceinline__ float bf2f(u32 lo16) { return __uint_as_float(lo16 << 16); }
__device__ __forceinline__ u16 f2bf(float f) {
    u32 u = __float_as_uint(f);
    return (u16)((u + 0x7FFFu + ((u >> 16) & 1u)) >> 16);
}
__device__ __forceinline__ u32 pack2(float a, float b) {
    return (u32)f2bf(a) | ((u32)f2bf(b) << 16);
}

// ---------------- k_wc: Wc = Won @ W1 (fp32), and c1 = b_on @ W1 + b1
__global__ __launch_bounds__(256) void k_wc(
    const float* __restrict__ Won, const float* __restrict__ W1,
    const float* __restrict__ b_on, const float* __restrict__ b1,
    float* __restrict__ Wc, float* __restrict__ c1)
{
    if (blockIdx.x < 64) {
        int tid = blockIdx.x * 256 + threadIdx.x;
        int i = tid >> 7, j = tid & 127;
        float s = 0.f;
        for (int k = 0; k < 128; k++) s = fmaf(Won[i * 128 + k], W1[k * 128 + j], s);
        Wc[tid] = s;
    } else if (threadIdx.x < 128) {
        int j = threadIdx.x;
        float s = b1[j];
        for (int k = 0; k < 128; k++) s = fmaf(b_on[k], W1[k * 128 + j], s);
        c1[j] = s;
    }
}

// ---------------- W fragment prep: slots 0=Won 1=Wtg 2=Wc 3=W2
// A-operand layout for mfma_f32_16x16x32_bf16 (W^T as A)
__global__ __launch_bounds__(256) void k_wfrag(
    const float* __restrict__ Won, const float* __restrict__ Wtg,
    const float* __restrict__ Wc, const float* __restrict__ W2,
    u16* __restrict__ Wfrag)
{
    int mat = blockIdx.x;
    const float* W = mat == 0 ? Won : (mat == 1 ? Wtg : (mat == 2 ? Wc : W2));
    uint4* out = (uint4*)(Wfrag + (size_t)mat * 16384);
    for (int s = threadIdx.x; s < 2048; s += 256) {
        int lane = s & 63;
        int n = ((s >> 8) << 4) + (lane & 15);
        int k0 = ((s >> 6) & 3) * 32 + (lane >> 4) * 8;
        u32 p[4];
#pragma unroll
        for (int jj = 0; jj < 4; jj++) {
            float a = W[(size_t)(k0 + 2 * jj) * 128 + n];
            float b = W[(size_t)(k0 + 2 * jj + 1) * 128 + n];
            p[jj] = pack2(a, b);
        }
        out[s] = make_uint4(p[0], p[1], p[2], p[3]);
    }
}

// ---------------- k_stage: XS[row][256] bf16 = [x(128) | x2(128)]
__global__ __launch_bounds__(256) void k_stage(
    const float* __restrict__ x, const float* __restrict__ perb,
    u16* __restrict__ XS, int N)
{
    int tid = blockIdx.x * 256 + threadIdx.x;
    if (tid >= N * 32) return;
    int row = tid >> 5, seg = tid & 31;
    float4 xv = *(const float4*)(x + (size_t)row * 128 + seg * 4);
    float4 pv = *(const float4*)(perb + (size_t)row * 128 + seg * 4);
    u16* r = XS + (size_t)row * 256 + seg * 4;
    *(uint2*)r = make_uint2(pack2(xv.x, xv.y), pack2(xv.z, xv.w));
    *(uint2*)(r + 128) = make_uint2(pack2(xv.x + pv.x, xv.y + pv.y), pack2(xv.z + pv.z, xv.w + pv.w));
}

// ---------------- CSR build
__global__ void k_count(const int* __restrict__ row, int* __restrict__ cnt, int E) {
    int e = blockIdx.x * blockDim.x + threadIdx.x;
    if (e < E) atomicAdd(&cnt[row[e]], 1);
}

__global__ __launch_bounds__(1024) void k_scan(const int* __restrict__ cnt, int* __restrict__ off, int N, int E) {
    __shared__ int ts[1024];
    int t = threadIdx.x;
    int CH = (N + 1023) >> 10;
    int lo = t * CH;
    int hi = lo + CH; if (hi > N) hi = N; if (lo > N) lo = N;
    int s = 0;
    for (int i = lo; i < hi; i++) s += cnt[i];
    ts[t] = s;
    __syncthreads();
    for (int d = 1; d < 1024; d <<= 1) {
        int add = (t >= d) ? ts[t - d] : 0;
        __syncthreads();
        ts[t] += add;
        __syncthreads();
    }
    int base = (t == 0) ? 0 : ts[t - 1];
    for (int i = lo; i < hi; i++) { off[i] = base; base += cnt[i]; }
    if (t == 0) off[N] = E;
}

__global__ void k_scatter(const int* __restrict__ row, const int* __restrict__ col, const float* __restrict__ w,
                          const int* __restrict__ off, int* __restrict__ fill,
                          int* __restrict__ ccol, float* __restrict__ cw, int E) {
    int e = blockIdx.x * blockDim.x + threadIdx.x;
    if (e < E) {
        int r = row[e];
        int pos = off[r] + atomicAdd(&fill[r], 1);
        ccol[pos] = col[e];
        cw[pos] = w[e];
    }
}

// ---------------- k_agg: wave per node; 512B coalesced gather per edge (x and x2 together)
__global__ __launch_bounds__(256) void k_agg(
    const u16* __restrict__ XS, const int* __restrict__ off,
    const int* __restrict__ ccol, const float* __restrict__ cw,
    u16* __restrict__ AG, int N)
{
    int wave = threadIdx.x >> 6, lane = threadIdx.x & 63;
    int node = blockIdx.x * 4 + wave;
    if (node >= N) return;
    int o0 = off[node], o1 = off[node + 1];
    float a0 = 0.f, a1 = 0.f, a2 = 0.f, a3 = 0.f;
#pragma unroll 4
    for (int e = o0; e < o1; e++) {
        int c = ccol[e];
        float w = cw[e];
        uint2 v = ((const uint2*)(XS + (size_t)c * 256))[lane];
        a0 = fmaf(w, bf2f(v.x & 0xffffu), a0);
        a1 = fmaf(w, bf2f(v.x >> 16), a1);
        a2 = fmaf(w, bf2f(v.y & 0xffffu), a2);
        a3 = fmaf(w, bf2f(v.y >> 16), a3);
    }
    ((uint2*)(AG + (size_t)node * 256))[lane] = make_uint2(pack2(a0, a1), pack2(a2, a3));
}

// ---------------- k_hemb: h1x = aggx@Wc + c1, h1y = aggx2@Wc + c1 (bf16),
//                  out-embed = x + perb + aggx2@Won + b_on (fp32)
__global__ __launch_bounds__(256) void k_hemb(
    const u16* __restrict__ AG, const u16* __restrict__ Wfrag,
    const float* __restrict__ c1, const float* __restrict__ b_on,
    const float* __restrict__ x, const float* __restrict__ perb,
    u16* __restrict__ h1x, u16* __restrict__ h1y, float* __restrict__ out, int N)
{
    const int wave = threadIdx.x >> 6, lane = threadIdx.x & 63;
    const int m = lane & 15, q = lane >> 4;
    const int grow = blockIdx.x * 64 + wave * 16 + m;
    const int rc = grow < N ? grow : N - 1;
    const bool valid = grow < N;
    const u16* ar = AG + (size_t)rc * 256;
    short8 fa[4], fb[4];
#pragma unroll
    for (int ks = 0; ks < 4; ks++) {
        int c0 = ks * 32 + q * 8;
        F8 t;
        t.u4 = *(const uint4*)(ar + c0);       fa[ks] = t.s8;   // agg_x
        t.u4 = *(const uint4*)(ar + 128 + c0); fb[ks] = t.s8;   // agg_x2
    }
    const uint4* wfWon = (const uint4*)Wfrag;
    const uint4* wfWc  = (const uint4*)(Wfrag + 2 * 16384);
#pragma unroll 2
    for (int ct = 0; ct < 8; ct++) {
        floatx4 ax = {0.f, 0.f, 0.f, 0.f}, ay = {0.f, 0.f, 0.f, 0.f}, em = {0.f, 0.f, 0.f, 0.f};
#pragma unroll
        for (int ks = 0; ks < 4; ks++) {
            F8 wc, wo;
            wc.u4 = wfWc[(ct * 4 + ks) * 64 + lane];
            wo.u4 = wfWon[(ct * 4 + ks) * 64 + lane];
            ax = __builtin_amdgcn_mfma_f32_16x16x32_bf16(wc.s8, fa[ks], ax, 0, 0, 0);
            ay = __builtin_amdgcn_mfma_f32_16x16x32_bf16(wc.s8, fb[ks], ay, 0, 0, 0);
            em = __builtin_amdgcn_mfma_f32_16x16x32_bf16(wo.s8, fb[ks], em, 0, 0, 0);
        }
        if (valid) {
            int c0 = ct * 16 + q * 4;
            float4 cv = *(const float4*)(c1 + c0);
            float4 bo = *(const float4*)(b_on + c0);
            float4 xv = *(const float4*)(x + (size_t)grow * 128 + c0);
            float4 pv = *(const float4*)(perb + (size_t)grow * 128 + c0);
            *(uint2*)(h1x + (size_t)grow * 128 + c0) =
                make_uint2(pack2(ax[0] + cv.x, ax[1] + cv.y), pack2(ax[2] + cv.z, ax[3] + cv.w));
            *(uint2*)(h1y + (size_t)grow * 128 + c0) =
                make_uint2(pack2(ay[0] + cv.x, ay[1] + cv.y), pack2(ay[2] + cv.z, ay[3] + cv.w));
            float4 o;
            o.x = xv.x + pv.x + em[0] + bo.x;
            o.y = xv.y + pv.y + em[1] + bo.y;
            o.z = xv.z + pv.z + em[2] + bo.z;
            o.w = xv.w + pv.w + em[3] + bo.w;
            *(float4*)(out + (size_t)grow * 128 + c0) = o;
        }
    }
}

// ---------------- BN stats over bf16 h1
__global__ __launch_bounds__(256) void k_bnstats(
    const u32* __restrict__ h1x32, const u32* __restrict__ h1y32,
    float* __restrict__ sums, int N)
{
    int c2 = threadIdx.x & 63, g = threadIdx.x >> 6;
    int per = (N + gridDim.x - 1) / gridDim.x;
    int r0 = blockIdx.x * per, r1 = r0 + per;
    if (r1 > N) r1 = N;
    float s[8] = {0.f, 0.f, 0.f, 0.f, 0.f, 0.f, 0.f, 0.f};
    for (int r = r0 + g; r < r1; r += 4) {
        u32 vx = h1x32[(size_t)r * 64 + c2];
        float lo = bf2f(vx & 0xffffu), hi = bf2f(vx >> 16);
        s[0] += lo; s[1] = fmaf(lo, lo, s[1]); s[2] += hi; s[3] = fmaf(hi, hi, s[3]);
        u32 vy = h1y32[(size_t)r * 64 + c2];
        lo = bf2f(vy & 0xffffu); hi = bf2f(vy >> 16);
        s[4] += lo; s[5] = fmaf(lo, lo, s[5]); s[6] += hi; s[7] = fmaf(hi, hi, s[7]);
    }
    __shared__ float red[256][8];
#pragma unroll
    for (int k = 0; k < 8; k++) red[threadIdx.x][k] = s[k];
    __syncthreads();
    if (g == 0) {
        float v[8];
#pragma unroll
        for (int k = 0; k < 8; k++)
            v[k] = red[c2][k] + red[c2 + 64][k] + red[c2 + 128][k] + red[c2 + 192][k];
        int c0 = 2 * c2, c1i = c0 + 1;
        atomicAdd(&sums[c0], v[0]);        atomicAdd(&sums[128 + c0], v[1]);
        atomicAdd(&sums[c1i], v[2]);       atomicAdd(&sums[128 + c1i], v[3]);
        atomicAdd(&sums[256 + c0], v[4]);  atomicAdd(&sums[384 + c0], v[5]);
        atomicAdd(&sums[256 + c1i], v[6]); atomicAdd(&sums[384 + c1i], v[7]);
    }
}

__global__ __launch_bounds__(128) void k_bnfin(
    const float* __restrict__ sums, const float* __restrict__ g, const float* __restrict__ beta,
    float* __restrict__ bnp, int N)
{
    int d = threadIdx.x;
    float inv = 1.0f / (float)N;
    float mux = sums[d] * inv;
    float varx = sums[128 + d] * inv - mux * mux;
    float isx = rsqrtf(varx + 1e-5f);
    bnp[d]       = g[d] * isx;
    bnp[128 + d] = beta[d] - mux * g[d] * isx;
    float muy = sums[256 + d] * inv;
    float vary = sums[384 + d] * inv - muy * muy;
    float isy = rsqrtf(vary + 1e-5f);
    bnp[256 + d] = g[d] * isy;
    bnp[384 + d] = beta[d] - muy * g[d] * isy;
}

// ---------------- k_loss: BN+PReLU -> px,py via W2; targets via Wtg from AG; cosine loss
__device__ __forceinline__ short8 bn_frag(const u16* hrow, const float* sc, const float* sh,
                                          int c0, float slope) {
    uint4 h = *(const uint4*)(hrow + c0);
    float4 s0 = *(const float4*)(sc + c0), s1 = *(const float4*)(sc + c0 + 4);
    float4 t0 = *(const float4*)(sh + c0), t1 = *(const float4*)(sh + c0 + 4);
    float v[8];
    v[0] = fmaf(bf2f(h.x & 0xffffu), s0.x, t0.x);
    v[1] = fmaf(bf2f(h.x >> 16),     s0.y, t0.y);
    v[2] = fmaf(bf2f(h.y & 0xffffu), s0.z, t0.z);
    v[3] = fmaf(bf2f(h.y >> 16),     s0.w, t0.w);
    v[4] = fmaf(bf2f(h.z & 0xffffu), s1.x, t1.x);
    v[5] = fmaf(bf2f(h.z >> 16),     s1.y, t1.y);
    v[6] = fmaf(bf2f(h.w & 0xffffu), s1.z, t1.z);
    v[7] = fmaf(bf2f(h.w >> 16),     s1.w, t1.w);
#pragma unroll
    for (int j = 0; j < 8; j++) v[j] = v[j] > 0.f ? v[j] : slope * v[j];
    F8 r;
    r.u4 = make_uint4(pack2(v[0], v[1]), pack2(v[2], v[3]), pack2(v[4], v[5]), pack2(v[6], v[7]));
    return r.s8;
}

__global__ __launch_bounds__(256) void k_loss(
    const u16* __restrict__ h1x, const u16* __restrict__ h1y,
    const u16* __restrict__ AG, const u16* __restrict__ Wfrag,
    const float* __restrict__ bnp, const float* __restrict__ prelu_a,
    const float* __restrict__ b2, const float* __restrict__ b_tg,
    float* __restrict__ loss, int N)
{
    const int wave = threadIdx.x >> 6, lane = threadIdx.x & 63;
    const int m = lane & 15, q = lane >> 4;
    const int grow = blockIdx.x * 64 + wave * 16 + m;
    const int rc = grow < N ? grow : N - 1;
    const bool valid = grow < N;
    const float slope = prelu_a[0];
    const u16* hx = h1x + (size_t)rc * 128;
    const u16* hy = h1y + (size_t)rc * 128;
    const u16* ar = AG + (size_t)rc * 256;
    short8 px8[4], py8[4], gx[4], gx2[4];
#pragma unroll
    for (int ks = 0; ks < 4; ks++) {
        int c0 = ks * 32 + q * 8;
        px8[ks] = bn_frag(hx, bnp, bnp + 128, c0, slope);
        py8[ks] = bn_frag(hy, bnp + 256, bnp + 384, c0, slope);
        F8 t;
        t.u4 = *(const uint4*)(ar + c0);       gx[ks] = t.s8;    // agg_x  -> target_y
        t.u4 = *(const uint4*)(ar + 128 + c0); gx2[ks] = t.s8;   // agg_x2 -> target_x
    }
    const uint4* wfTg = (const uint4*)(Wfrag + 1 * 16384);
    const uint4* wfW2 = (const uint4*)(Wfrag + 3 * 16384);
    float pp = 0.f, pt = 0.f, tt = 0.f, qq = 0.f, qs = 0.f, ss = 0.f;
#pragma unroll 1
    for (int ct = 0; ct < 8; ct++) {
        floatx4 ax = {0.f, 0.f, 0.f, 0.f}, ay = {0.f, 0.f, 0.f, 0.f};
        floatx4 atx = {0.f, 0.f, 0.f, 0.f}, aty = {0.f, 0.f, 0.f, 0.f};
#pragma unroll
        for (int ks = 0; ks < 4; ks++) {
            F8 w2, wt;
            w2.u4 = wfW2[(ct * 4 + ks) * 64 + lane];
            wt.u4 = wfTg[(ct * 4 + ks) * 64 + lane];
            ax  = __builtin_amdgcn_mfma_f32_16x16x32_bf16(w2.s8, px8[ks], ax, 0, 0, 0);
            ay  = __builtin_amdgcn_mfma_f32_16x16x32_bf16(w2.s8, py8[ks], ay, 0, 0, 0);
            atx = __builtin_amdgcn_mfma_f32_16x16x32_bf16(wt.s8, gx2[ks], atx, 0, 0, 0);
            aty = __builtin_amdgcn_mfma_f32_16x16x32_bf16(wt.s8, gx[ks], aty, 0, 0, 0);
        }
        int c0 = ct * 16 + q * 4;
        float4 bv = *(const float4*)(b2 + c0);
        float4 tb = *(const float4*)(b_tg + c0);
#pragma unroll
        for (int j = 0; j < 4; j++) {
            float bvj = j == 0 ? bv.x : (j == 1 ? bv.y : (j == 2 ? bv.z : bv.w));
            float tbj = j == 0 ? tb.x : (j == 1 ? tb.y : (j == 2 ? tb.z : tb.w));
            float pxv = ax[j] + bvj, txv = atx[j] + tbj;
            float pyv = ay[j] + bvj, tyv = aty[j] + tbj;
            pp = fmaf(pxv, pxv, pp); pt = fmaf(pxv, txv, pt); tt = fmaf(txv, txv, tt);
            qq = fmaf(pyv, pyv, qq); qs = fmaf(pyv, tyv, qs); ss = fmaf(tyv, tyv, ss);
        }
    }
    pp += __shfl_xor(pp, 16); pt += __shfl_xor(pt, 16); tt += __shfl_xor(tt, 16);
    qq += __shfl_xor(qq, 16); qs += __shfl_xor(qs, 16); ss += __shfl_xor(ss, 16);
    pp += __shfl_xor(pp, 32); pt += __shfl_xor(pt, 32); tt += __shfl_xor(tt, 32);
    qq += __shfl_xor(qq, 32); qs += __shfl_xor(qs, 32); ss += __shfl_xor(ss, 32);
    float cx = pt / (fmaxf(sqrtf(pp), 1e-12f) * fmaxf(sqrtf(tt), 1e-12f));
    float cy = qs / (fmaxf(sqrtf(qq), 1e-12f) * fmaxf(sqrtf(ss), 1e-12f));
    float lsum = valid ? (4.f - 2.f * cx - 2.f * cy) : 0.f;
    lsum += __shfl_xor(lsum, 1); lsum += __shfl_xor(lsum, 2);
    lsum += __shfl_xor(lsum, 4); lsum += __shfl_xor(lsum, 8);
    if (lane == 0) atomicAdd(loss, lsum);
}

// ---------------- k_fin: loss scalar
__global__ void k_fin(const float* __restrict__ loss, float* __restrict__ out, int N) {
    if (threadIdx.x == 0) out[(size_t)N * 128] = loss[0] * (1.0f / (float)N);
}

extern "C" void kernel_launch(void* const* d_in, const int* in_sizes, int n_in,
                              void* d_out, int out_size, void* d_ws, size_t ws_size,
                              hipStream_t stream)
{
    const float* x    = (const float*)d_in[0];
    const float* perb = (const float*)d_in[1];
    const int*   erow = (const int*)d_in[2];
    const int*   ecol = (const int*)d_in[3];
    const float* ew   = (const float*)d_in[4];
    const float* Won  = (const float*)d_in[5];
    const float* bon  = (const float*)d_in[6];
    const float* Wtg  = (const float*)d_in[7];
    const float* btg  = (const float*)d_in[8];
    const float* W1   = (const float*)d_in[9];
    const float* b1   = (const float*)d_in[10];
    const float* bng  = (const float*)d_in[11];
    const float* bnb  = (const float*)d_in[12];
    const float* pra  = (const float*)d_in[13];
    const float* W2   = (const float*)d_in[14];
    const float* b2   = (const float*)d_in[15];
    float* out = (float*)d_out;

    const int N = in_sizes[0] / 128;
    const int E = in_sizes[2];

    char* ws = (char*)d_ws;
    u16* XS  = (u16*)ws;                                  // N*256 bf16 = N*512B
    u16* AG  = (u16*)(ws + (size_t)N * 512);              // N*256 bf16
    u16* h1x = (u16*)(ws + (size_t)N * 1024);             // N*128 bf16
    u16* h1y = (u16*)(ws + (size_t)N * 1024 + (size_t)N * 256);

    char* p = ws + (size_t)N * 1024 + (size_t)N * 512;
    const size_t szcnt = (((size_t)(N + 16) * 4) + 63) & ~(size_t)63;
    int* cnt  = (int*)p;      p += szcnt;
    int* fill = (int*)p;      p += szcnt;
    float* sums = (float*)p;  p += 2048;
    float* loss = (float*)p;  p += 64;
    size_t zero_bytes = (size_t)(p - (char*)cnt);
    int* off  = (int*)p;      p += szcnt;
    int* ccol = (int*)p;      p += (((size_t)E * 4) + 63) & ~(size_t)63;
    float* cw = (float*)p;    p += (((size_t)E * 4) + 63) & ~(size_t)63;
    float* c1 = (float*)p;    p += 512;
    float* bnp = (float*)p;   p += 2048;
    float* Wc = (float*)p;    p += 128 * 128 * 4;
    u16* Wfrag = (u16*)p;     p += 4 * 16384 * 2;

    hipMemsetAsync(cnt, 0, zero_bytes, stream);

    const int nb64 = (N + 63) / 64;
    k_wc<<<65, 256, 0, stream>>>(Won, W1, bon, b1, Wc, c1);
    k_wfrag<<<4, 256, 0, stream>>>(Won, Wtg, Wc, W2, Wfrag);
    k_stage<<<(N * 32 + 255) / 256, 256, 0, stream>>>(x, perb, XS, N);
    k_count<<<(E + 255) / 256, 256, 0, stream>>>(erow, cnt, E);
    k_scan<<<1, 1024, 0, stream>>>(cnt, off, N, E);
    k_scatter<<<(E + 255) / 256, 256, 0, stream>>>(erow, ecol, ew, off, fill, ccol, cw, E);
    k_agg<<<(N + 3) / 4, 256, 0, stream>>>(XS, off, ccol, cw, AG, N);
    k_hemb<<<nb64, 256, 0, stream>>>(AG, Wfrag, c1, bon, x, perb, h1x, h1y, out, N);
    k_bnstats<<<128, 256, 0, stream>>>((const u32*)h1x, (const u32*)h1y, sums, N);
    k_bnfin<<<1, 128, 0, stream>>>(sums, bng, bnb, bnp, N);
    k_loss<<<nb64, 256, 0, stream>>>(h1x, h1y, AG, Wfrag, bnp, pra, b2, btg, loss, N);
    k_fin<<<1, 64, 0, stream>>>(loss, out, N);
}

// Round 4
// 420.608 us; speedup vs baseline: 1.8767x; 1.1853x over previous
//
#include <hip/hip_runtime.h>

typedef unsigned int u32;
typedef unsigned short u16;
typedef __attribute__((ext_vector_type(8))) short short8;
typedef __attribute__((ext_vector_type(4))) float floatx4;

union F8 { uint4 u4; short8 s8; };

__device__ __forceinline__ float bf2f(u32 lo16) { return __uint_as_float(lo16 << 16); }
__device__ __forceinline__ u16 f2bf(float f) {
    u32 u = __float_as_uint(f);
    return (u16)((u + 0x7FFFu + ((u >> 16) & 1u)) >> 16);
}
__device__ __forceinline__ u32 pack2(float a, float b) {
    return (u32)f2bf(a) | ((u32)f2bf(b) << 16);
}

// ---------------- k_wc: Wc = Won @ W1 (fp32), and c1 = b_on @ W1 + b1
__global__ __launch_bounds__(256) void k_wc(
    const float* __restrict__ Won, const float* __restrict__ W1,
    const float* __restrict__ b_on, const float* __restrict__ b1,
    float* __restrict__ Wc, float* __restrict__ c1)
{
    if (blockIdx.x < 64) {
        int tid = blockIdx.x * 256 + threadIdx.x;
        int i = tid >> 7, j = tid & 127;
        float s = 0.f;
        for (int k = 0; k < 128; k++) s = fmaf(Won[i * 128 + k], W1[k * 128 + j], s);
        Wc[tid] = s;
    } else if (threadIdx.x < 128) {
        int j = threadIdx.x;
        float s = b1[j];
        for (int k = 0; k < 128; k++) s = fmaf(b_on[k], W1[k * 128 + j], s);
        c1[j] = s;
    }
}

// ---------------- W fragment prep: slots 0=Won 1=Wtg 2=Wc 3=W2
__global__ __launch_bounds__(256) void k_wfrag(
    const float* __restrict__ Won, const float* __restrict__ Wtg,
    const float* __restrict__ Wc, const float* __restrict__ W2,
    u16* __restrict__ Wfrag)
{
    int mat = blockIdx.x;
    const float* W = mat == 0 ? Won : (mat == 1 ? Wtg : (mat == 2 ? Wc : W2));
    uint4* out = (uint4*)(Wfrag + (size_t)mat * 16384);
    for (int s = threadIdx.x; s < 2048; s += 256) {
        int lane = s & 63;
        int n = ((s >> 8) << 4) + (lane & 15);
        int k0 = ((s >> 6) & 3) * 32 + (lane >> 4) * 8;
        u32 p[4];
#pragma unroll
        for (int jj = 0; jj < 4; jj++) {
            float a = W[(size_t)(k0 + 2 * jj) * 128 + n];
            float b = W[(size_t)(k0 + 2 * jj + 1) * 128 + n];
            p[jj] = pack2(a, b);
        }
        out[s] = make_uint4(p[0], p[1], p[2], p[3]);
    }
}

// ---------------- k_stage: XS[row][256] bf16 = [x(128) | x2(128)]
__global__ __launch_bounds__(256) void k_stage(
    const float* __restrict__ x, const float* __restrict__ perb,
    u16* __restrict__ XS, int N)
{
    int tid = blockIdx.x * 256 + threadIdx.x;
    if (tid >= N * 32) return;
    int row = tid >> 5, seg = tid & 31;
    float4 xv = *(const float4*)(x + (size_t)row * 128 + seg * 4);
    float4 pv = *(const float4*)(perb + (size_t)row * 128 + seg * 4);
    u16* r = XS + (size_t)row * 256 + seg * 4;
    *(uint2*)r = make_uint2(pack2(xv.x, xv.y), pack2(xv.z, xv.w));
    *(uint2*)(r + 128) = make_uint2(pack2(xv.x + pv.x, xv.y + pv.y), pack2(xv.z + pv.z, xv.w + pv.w));
}

// ---------------- CSR build
__global__ void k_count(const int* __restrict__ row, int* __restrict__ cnt, int E) {
    int e = blockIdx.x * blockDim.x + threadIdx.x;
    if (e < E) atomicAdd(&cnt[row[e]], 1);
}

#define SCAN_CHUNK 512
// block partial sums of cnt
__global__ __launch_bounds__(256) void k_bsum(const int* __restrict__ cnt, int* __restrict__ bsum, int N) {
    int t = threadIdx.x;
    int i0 = blockIdx.x * SCAN_CHUNK + t;
    int s = 0;
    if (i0 < N) s += cnt[i0];
    if (i0 + 256 < N) s += cnt[i0 + 256];
    __shared__ int red[256];
    red[t] = s; __syncthreads();
    for (int d = 128; d > 0; d >>= 1) { if (t < d) red[t] += red[t + d]; __syncthreads(); }
    if (t == 0) bsum[blockIdx.x] = red[0];
}

// per-chunk exclusive scan + global base from bsum prefix
__global__ __launch_bounds__(256) void k_scan2(
    const int* __restrict__ cnt, const int* __restrict__ bsum,
    int* __restrict__ off, int N, int E)
{
    int b = blockIdx.x, t = threadIdx.x;
    __shared__ int red[256];
    __shared__ int sc[257];
    __shared__ int sbase;
    int ps = 0;
    for (int i = t; i < b; i += 256) ps += bsum[i];
    red[t] = ps; __syncthreads();
    for (int d = 128; d > 0; d >>= 1) { if (t < d) red[t] += red[t + d]; __syncthreads(); }
    if (t == 0) sbase = red[0];
    __syncthreads();
    int base = b * SCAN_CHUNK;
    int i0 = base + 2 * t, i1 = i0 + 1;
    int v0 = (i0 < N) ? cnt[i0] : 0;
    int v1 = (i1 < N) ? cnt[i1] : 0;
    int tsum = v0 + v1;
    sc[t] = tsum; __syncthreads();
    for (int d = 1; d < 256; d <<= 1) {
        int add = (t >= d) ? sc[t - d] : 0;
        __syncthreads();
        sc[t] += add;
        __syncthreads();
    }
    int excl = sbase + sc[t] - tsum;
    if (i0 < N) off[i0] = excl;
    if (i1 < N) off[i1] = excl + v0;
    if (b == 0 && t == 0) off[N] = E;
}

__global__ void k_scatter(const int* __restrict__ row, const int* __restrict__ col, const float* __restrict__ w,
                          const int* __restrict__ off, int* __restrict__ fill,
                          int* __restrict__ ccol, float* __restrict__ cw, int E) {
    int e = blockIdx.x * blockDim.x + threadIdx.x;
    if (e < E) {
        int r = row[e];
        int pos = off[r] + atomicAdd(&fill[r], 1);
        ccol[pos] = col[e];
        cw[pos] = w[e];
    }
}

// ---------------- k_agg: wave per node; 512B coalesced gather per edge (x and x2 together)
__global__ __launch_bounds__(256) void k_agg(
    const u16* __restrict__ XS, const int* __restrict__ off,
    const int* __restrict__ ccol, const float* __restrict__ cw,
    u16* __restrict__ AG, int N)
{
    int wave = threadIdx.x >> 6, lane = threadIdx.x & 63;
    int node = blockIdx.x * 4 + wave;
    if (node >= N) return;
    int o0 = off[node], o1 = off[node + 1];
    float a0 = 0.f, a1 = 0.f, a2 = 0.f, a3 = 0.f;
#pragma unroll 4
    for (int e = o0; e < o1; e++) {
        int c = ccol[e];
        float w = cw[e];
        uint2 v = ((const uint2*)(XS + (size_t)c * 256))[lane];
        a0 = fmaf(w, bf2f(v.x & 0xffffu), a0);
        a1 = fmaf(w, bf2f(v.x >> 16), a1);
        a2 = fmaf(w, bf2f(v.y & 0xffffu), a2);
        a3 = fmaf(w, bf2f(v.y >> 16), a3);
    }
    ((uint2*)(AG + (size_t)node * 256))[lane] = make_uint2(pack2(a0, a1), pack2(a2, a3));
}

// ---------------- k_hemb
__global__ __launch_bounds__(256) void k_hemb(
    const u16* __restrict__ AG, const u16* __restrict__ Wfrag,
    const float* __restrict__ c1, const float* __restrict__ b_on,
    const float* __restrict__ x, const float* __restrict__ perb,
    u16* __restrict__ h1x, u16* __restrict__ h1y, float* __restrict__ out, int N)
{
    const int wave = threadIdx.x >> 6, lane = threadIdx.x & 63;
    const int m = lane & 15, q = lane >> 4;
    const int grow = blockIdx.x * 64 + wave * 16 + m;
    const int rc = grow < N ? grow : N - 1;
    const bool valid = grow < N;
    const u16* ar = AG + (size_t)rc * 256;
    short8 fa[4], fb[4];
#pragma unroll
    for (int ks = 0; ks < 4; ks++) {
        int c0 = ks * 32 + q * 8;
        F8 t;
        t.u4 = *(const uint4*)(ar + c0);       fa[ks] = t.s8;   // agg_x
        t.u4 = *(const uint4*)(ar + 128 + c0); fb[ks] = t.s8;   // agg_x2
    }
    const uint4* wfWon = (const uint4*)Wfrag;
    const uint4* wfWc  = (const uint4*)(Wfrag + 2 * 16384);
#pragma unroll 2
    for (int ct = 0; ct < 8; ct++) {
        floatx4 ax = {0.f, 0.f, 0.f, 0.f}, ay = {0.f, 0.f, 0.f, 0.f}, em = {0.f, 0.f, 0.f, 0.f};
#pragma unroll
        for (int ks = 0; ks < 4; ks++) {
            F8 wc, wo;
            wc.u4 = wfWc[(ct * 4 + ks) * 64 + lane];
            wo.u4 = wfWon[(ct * 4 + ks) * 64 + lane];
            ax = __builtin_amdgcn_mfma_f32_16x16x32_bf16(wc.s8, fa[ks], ax, 0, 0, 0);
            ay = __builtin_amdgcn_mfma_f32_16x16x32_bf16(wc.s8, fb[ks], ay, 0, 0, 0);
            em = __builtin_amdgcn_mfma_f32_16x16x32_bf16(wo.s8, fb[ks], em, 0, 0, 0);
        }
        if (valid) {
            int c0 = ct * 16 + q * 4;
            float4 cv = *(const float4*)(c1 + c0);
            float4 bo = *(const float4*)(b_on + c0);
            float4 xv = *(const float4*)(x + (size_t)grow * 128 + c0);
            float4 pv = *(const float4*)(perb + (size_t)grow * 128 + c0);
            *(uint2*)(h1x + (size_t)grow * 128 + c0) =
                make_uint2(pack2(ax[0] + cv.x, ax[1] + cv.y), pack2(ax[2] + cv.z, ax[3] + cv.w));
            *(uint2*)(h1y + (size_t)grow * 128 + c0) =
                make_uint2(pack2(ay[0] + cv.x, ay[1] + cv.y), pack2(ay[2] + cv.z, ay[3] + cv.w));
            float4 o;
            o.x = xv.x + pv.x + em[0] + bo.x;
            o.y = xv.y + pv.y + em[1] + bo.y;
            o.z = xv.z + pv.z + em[2] + bo.z;
            o.w = xv.w + pv.w + em[3] + bo.w;
            *(float4*)(out + (size_t)grow * 128 + c0) = o;
        }
    }
}

// ---------------- BN stats over bf16 h1
__global__ __launch_bounds__(256) void k_bnstats(
    const u32* __restrict__ h1x32, const u32* __restrict__ h1y32,
    float* __restrict__ sums, int N)
{
    int c2 = threadIdx.x & 63, g = threadIdx.x >> 6;
    int per = (N + gridDim.x - 1) / gridDim.x;
    int r0 = blockIdx.x * per, r1 = r0 + per;
    if (r1 > N) r1 = N;
    float s[8] = {0.f, 0.f, 0.f, 0.f, 0.f, 0.f, 0.f, 0.f};
    for (int r = r0 + g; r < r1; r += 4) {
        u32 vx = h1x32[(size_t)r * 64 + c2];
        float lo = bf2f(vx & 0xffffu), hi = bf2f(vx >> 16);
        s[0] += lo; s[1] = fmaf(lo, lo, s[1]); s[2] += hi; s[3] = fmaf(hi, hi, s[3]);
        u32 vy = h1y32[(size_t)r * 64 + c2];
        lo = bf2f(vy & 0xffffu); hi = bf2f(vy >> 16);
        s[4] += lo; s[5] = fmaf(lo, lo, s[5]); s[6] += hi; s[7] = fmaf(hi, hi, s[7]);
    }
    __shared__ float red[256][8];
#pragma unroll
    for (int k = 0; k < 8; k++) red[threadIdx.x][k] = s[k];
    __syncthreads();
    if (g == 0) {
        float v[8];
#pragma unroll
        for (int k = 0; k < 8; k++)
            v[k] = red[c2][k] + red[c2 + 64][k] + red[c2 + 128][k] + red[c2 + 192][k];
        int c0 = 2 * c2, c1i = c0 + 1;
        atomicAdd(&sums[c0], v[0]);        atomicAdd(&sums[128 + c0], v[1]);
        atomicAdd(&sums[c1i], v[2]);       atomicAdd(&sums[128 + c1i], v[3]);
        atomicAdd(&sums[256 + c0], v[4]);  atomicAdd(&sums[384 + c0], v[5]);
        atomicAdd(&sums[256 + c1i], v[6]); atomicAdd(&sums[384 + c1i], v[7]);
    }
}

__global__ __launch_bounds__(128) void k_bnfin(
    const float* __restrict__ sums, const float* __restrict__ g, const float* __restrict__ beta,
    float* __restrict__ bnp, int N)
{
    int d = threadIdx.x;
    float inv = 1.0f / (float)N;
    float mux = sums[d] * inv;
    float varx = sums[128 + d] * inv - mux * mux;
    float isx = rsqrtf(varx + 1e-5f);
    bnp[d]       = g[d] * isx;
    bnp[128 + d] = beta[d] - mux * g[d] * isx;
    float muy = sums[256 + d] * inv;
    float vary = sums[384 + d] * inv - muy * muy;
    float isy = rsqrtf(vary + 1e-5f);
    bnp[256 + d] = g[d] * isy;
    bnp[384 + d] = beta[d] - muy * g[d] * isy;
}

// ---------------- k_loss
__device__ __forceinline__ short8 bn_frag(const u16* hrow, const float* sc, const float* sh,
                                          int c0, float slope) {
    uint4 h = *(const uint4*)(hrow + c0);
    float4 s0 = *(const float4*)(sc + c0), s1 = *(const float4*)(sc + c0 + 4);
    float4 t0 = *(const float4*)(sh + c0), t1 = *(const float4*)(sh + c0 + 4);
    float v[8];
    v[0] = fmaf(bf2f(h.x & 0xffffu), s0.x, t0.x);
    v[1] = fmaf(bf2f(h.x >> 16),     s0.y, t0.y);
    v[2] = fmaf(bf2f(h.y & 0xffffu), s0.z, t0.z);
    v[3] = fmaf(bf2f(h.y >> 16),     s0.w, t0.w);
    v[4] = fmaf(bf2f(h.z & 0xffffu), s1.x, t1.x);
    v[5] = fmaf(bf2f(h.z >> 16),     s1.y, t1.y);
    v[6] = fmaf(bf2f(h.w & 0xffffu), s1.z, t1.z);
    v[7] = fmaf(bf2f(h.w >> 16),     s1.w, t1.w);
#pragma unroll
    for (int j = 0; j < 8; j++) v[j] = v[j] > 0.f ? v[j] : slope * v[j];
    F8 r;
    r.u4 = make_uint4(pack2(v[0], v[1]), pack2(v[2], v[3]), pack2(v[4], v[5]), pack2(v[6], v[7]));
    return r.s8;
}

__global__ __launch_bounds__(256) void k_loss(
    const u16* __restrict__ h1x, const u16* __restrict__ h1y,
    const u16* __restrict__ AG, const u16* __restrict__ Wfrag,
    const float* __restrict__ bnp, const float* __restrict__ prelu_a,
    const float* __restrict__ b2, const float* __restrict__ b_tg,
    float* __restrict__ loss, int N)
{
    const int wave = threadIdx.x >> 6, lane = threadIdx.x & 63;
    const int m = lane & 15, q = lane >> 4;
    const int grow = blockIdx.x * 64 + wave * 16 + m;
    const int rc = grow < N ? grow : N - 1;
    const bool valid = grow < N;
    const float slope = prelu_a[0];
    const u16* hx = h1x + (size_t)rc * 128;
    const u16* hy = h1y + (size_t)rc * 128;
    const u16* ar = AG + (size_t)rc * 256;
    short8 px8[4], py8[4], gx[4], gx2[4];
#pragma unroll
    for (int ks = 0; ks < 4; ks++) {
        int c0 = ks * 32 + q * 8;
        px8[ks] = bn_frag(hx, bnp, bnp + 128, c0, slope);
        py8[ks] = bn_frag(hy, bnp + 256, bnp + 384, c0, slope);
        F8 t;
        t.u4 = *(const uint4*)(ar + c0);       gx[ks] = t.s8;    // agg_x  -> target_y
        t.u4 = *(const uint4*)(ar + 128 + c0); gx2[ks] = t.s8;   // agg_x2 -> target_x
    }
    const uint4* wfTg = (const uint4*)(Wfrag + 1 * 16384);
    const uint4* wfW2 = (const uint4*)(Wfrag + 3 * 16384);
    float pp = 0.f, pt = 0.f, tt = 0.f, qq = 0.f, qs = 0.f, ss = 0.f;
#pragma unroll 1
    for (int ct = 0; ct < 8; ct++) {
        floatx4 ax = {0.f, 0.f, 0.f, 0.f}, ay = {0.f, 0.f, 0.f, 0.f};
        floatx4 atx = {0.f, 0.f, 0.f, 0.f}, aty = {0.f, 0.f, 0.f, 0.f};
#pragma unroll
        for (int ks = 0; ks < 4; ks++) {
            F8 w2, wt;
            w2.u4 = wfW2[(ct * 4 + ks) * 64 + lane];
            wt.u4 = wfTg[(ct * 4 + ks) * 64 + lane];
            ax  = __builtin_amdgcn_mfma_f32_16x16x32_bf16(w2.s8, px8[ks], ax, 0, 0, 0);
            ay  = __builtin_amdgcn_mfma_f32_16x16x32_bf16(w2.s8, py8[ks], ay, 0, 0, 0);
            atx = __builtin_amdgcn_mfma_f32_16x16x32_bf16(wt.s8, gx2[ks], atx, 0, 0, 0);
            aty = __builtin_amdgcn_mfma_f32_16x16x32_bf16(wt.s8, gx[ks], aty, 0, 0, 0);
        }
        int c0 = ct * 16 + q * 4;
        float4 bv = *(const float4*)(b2 + c0);
        float4 tb = *(const float4*)(b_tg + c0);
#pragma unroll
        for (int j = 0; j < 4; j++) {
            float bvj = j == 0 ? bv.x : (j == 1 ? bv.y : (j == 2 ? bv.z : bv.w));
            float tbj = j == 0 ? tb.x : (j == 1 ? tb.y : (j == 2 ? tb.z : tb.w));
            float pxv = ax[j] + bvj, txv = atx[j] + tbj;
            float pyv = ay[j] + bvj, tyv = aty[j] + tbj;
            pp = fmaf(pxv, pxv, pp); pt = fmaf(pxv, txv, pt); tt = fmaf(txv, txv, tt);
            qq = fmaf(pyv, pyv, qq); qs = fmaf(pyv, tyv, qs); ss = fmaf(tyv, tyv, ss);
        }
    }
    pp += __shfl_xor(pp, 16); pt += __shfl_xor(pt, 16); tt += __shfl_xor(tt, 16);
    qq += __shfl_xor(qq, 16); qs += __shfl_xor(qs, 16); ss += __shfl_xor(ss, 16);
    pp += __shfl_xor(pp, 32); pt += __shfl_xor(pt, 32); tt += __shfl_xor(tt, 32);
    qq += __shfl_xor(qq, 32); qs += __shfl_xor(qs, 32); ss += __shfl_xor(ss, 32);
    float cx = pt / (fmaxf(sqrtf(pp), 1e-12f) * fmaxf(sqrtf(tt), 1e-12f));
    float cy = qs / (fmaxf(sqrtf(qq), 1e-12f) * fmaxf(sqrtf(ss), 1e-12f));
    float lsum = valid ? (4.f - 2.f * cx - 2.f * cy) : 0.f;
    lsum += __shfl_xor(lsum, 1); lsum += __shfl_xor(lsum, 2);
    lsum += __shfl_xor(lsum, 4); lsum += __shfl_xor(lsum, 8);
    if (lane == 0) atomicAdd(loss, lsum);
}

// ---------------- k_fin: loss scalar
__global__ void k_fin(const float* __restrict__ loss, float* __restrict__ out, int N) {
    if (threadIdx.x == 0) out[(size_t)N * 128] = loss[0] * (1.0f / (float)N);
}

extern "C" void kernel_launch(void* const* d_in, const int* in_sizes, int n_in,
                              void* d_out, int out_size, void* d_ws, size_t ws_size,
                              hipStream_t stream)
{
    const float* x    = (const float*)d_in[0];
    const float* perb = (const float*)d_in[1];
    const int*   erow = (const int*)d_in[2];
    const int*   ecol = (const int*)d_in[3];
    const float* ew   = (const float*)d_in[4];
    const float* Won  = (const float*)d_in[5];
    const float* bon  = (const float*)d_in[6];
    const float* Wtg  = (const float*)d_in[7];
    const float* btg  = (const float*)d_in[8];
    const float* W1   = (const float*)d_in[9];
    const float* b1   = (const float*)d_in[10];
    const float* bng  = (const float*)d_in[11];
    const float* bnb  = (const float*)d_in[12];
    const float* pra  = (const float*)d_in[13];
    const float* W2   = (const float*)d_in[14];
    const float* b2   = (const float*)d_in[15];
    float* out = (float*)d_out;

    const int N = in_sizes[0] / 128;
    const int E = in_sizes[2];

    char* ws = (char*)d_ws;
    u16* XS  = (u16*)ws;                                  // N*256 bf16 = N*512B
    u16* AG  = (u16*)(ws + (size_t)N * 512);              // N*256 bf16
    u16* h1x = (u16*)(ws + (size_t)N * 1024);             // N*128 bf16
    u16* h1y = (u16*)(ws + (size_t)N * 1024 + (size_t)N * 256);

    char* p = ws + (size_t)N * 1024 + (size_t)N * 512;
    const size_t szcnt = (((size_t)(N + 16) * 4) + 63) & ~(size_t)63;
    int* cnt  = (int*)p;      p += szcnt;
    int* fill = (int*)p;      p += szcnt;
    float* sums = (float*)p;  p += 2048;
    float* loss = (float*)p;  p += 64;
    size_t zero_bytes = (size_t)(p - (char*)cnt);
    int* off  = (int*)p;      p += szcnt;
    int* bsum = (int*)p;      p += 4096;
    int* ccol = (int*)p;      p += (((size_t)E * 4) + 63) & ~(size_t)63;
    float* cw = (float*)p;    p += (((size_t)E * 4) + 63) & ~(size_t)63;
    float* c1 = (float*)p;    p += 512;
    float* bnp = (float*)p;   p += 2048;
    float* Wc = (float*)p;    p += 128 * 128 * 4;
    u16* Wfrag = (u16*)p;     p += 4 * 16384 * 2;

    hipMemsetAsync(cnt, 0, zero_bytes, stream);

    const int nb64 = (N + 63) / 64;
    const int nbscan = (N + SCAN_CHUNK - 1) / SCAN_CHUNK;
    k_wc<<<65, 256, 0, stream>>>(Won, W1, bon, b1, Wc, c1);
    k_wfrag<<<4, 256, 0, stream>>>(Won, Wtg, Wc, W2, Wfrag);
    k_stage<<<(N * 32 + 255) / 256, 256, 0, stream>>>(x, perb, XS, N);
    k_count<<<(E + 255) / 256, 256, 0, stream>>>(erow, cnt, E);
    k_bsum<<<nbscan, 256, 0, stream>>>(cnt, bsum, N);
    k_scan2<<<nbscan, 256, 0, stream>>>(cnt, bsum, off, N, E);
    k_scatter<<<(E + 255) / 256, 256, 0, stream>>>(erow, ecol, ew, off, fill, ccol, cw, E);
    k_agg<<<(N + 3) / 4, 256, 0, stream>>>(XS, off, ccol, cw, AG, N);
    k_hemb<<<nb64, 256, 0, stream>>>(AG, Wfrag, c1, bon, x, perb, h1x, h1y, out, N);
    k_bnstats<<<128, 256, 0, stream>>>((const u32*)h1x, (const u32*)h1y, sums, N);
    k_bnfin<<<1, 128, 0, stream>>>(sums, bng, bnb, bnp, N);
    k_loss<<<nb64, 256, 0, stream>>>(h1x, h1y, AG, Wfrag, bnp, pra, b2, btg, loss, N);
    k_fin<<<1, 64, 0, stream>>>(loss, out, N);
}

// Round 5
// 413.615 us; speedup vs baseline: 1.9085x; 1.0169x over previous
//
#include <hip/hip_runtime.h>

typedef unsigned int u32;
typedef unsigned short u16;
typedef __attribute__((ext_vector_type(8))) short short8;
typedef __attribute__((ext_vector_type(4))) float floatx4;

union F8 { uint4 u4; short8 s8; };

__device__ __forceinline__ float bf2f(u32 lo16) { return __uint_as_float(lo16 << 16); }
__device__ __forceinline__ u16 f2bf(float f) {
    u32 u = __float_as_uint(f);
    return (u16)((u + 0x7FFFu + ((u >> 16) & 1u)) >> 16);
}
__device__ __forceinline__ u32 pack2(float a, float b) {
    return (u32)f2bf(a) | ((u32)f2bf(b) << 16);
}

// ---------------- k_wc: Wc = Won @ W1 (fp32), and c1 = b_on @ W1 + b1
__global__ __launch_bounds__(256) void k_wc(
    const float* __restrict__ Won, const float* __restrict__ W1,
    const float* __restrict__ b_on, const float* __restrict__ b1,
    float* __restrict__ Wc, float* __restrict__ c1)
{
    if (blockIdx.x < 64) {
        int tid = blockIdx.x * 256 + threadIdx.x;
        int i = tid >> 7, j = tid & 127;
        float s = 0.f;
        for (int k = 0; k < 128; k++) s = fmaf(Won[i * 128 + k], W1[k * 128 + j], s);
        Wc[tid] = s;
    } else if (threadIdx.x < 128) {
        int j = threadIdx.x;
        float s = b1[j];
        for (int k = 0; k < 128; k++) s = fmaf(b_on[k], W1[k * 128 + j], s);
        c1[j] = s;
    }
}

// ---------------- W fragment prep: slots 0=Won 1=Wtg 2=Wc 3=W2
__global__ __launch_bounds__(256) void k_wfrag(
    const float* __restrict__ Won, const float* __restrict__ Wtg,
    const float* __restrict__ Wc, const float* __restrict__ W2,
    u16* __restrict__ Wfrag)
{
    int mat = blockIdx.x;
    const float* W = mat == 0 ? Won : (mat == 1 ? Wtg : (mat == 2 ? Wc : W2));
    uint4* out = (uint4*)(Wfrag + (size_t)mat * 16384);
    for (int s = threadIdx.x; s < 2048; s += 256) {
        int lane = s & 63;
        int n = ((s >> 8) << 4) + (lane & 15);
        int k0 = ((s >> 6) & 3) * 32 + (lane >> 4) * 8;
        u32 p[4];
#pragma unroll
        for (int jj = 0; jj < 4; jj++) {
            float a = W[(size_t)(k0 + 2 * jj) * 128 + n];
            float b = W[(size_t)(k0 + 2 * jj + 1) * 128 + n];
            p[jj] = pack2(a, b);
        }
        out[s] = make_uint4(p[0], p[1], p[2], p[3]);
    }
}

// ---------------- k_stage: XS[row][256] bf16 = [x(128) | x2(128)]
__global__ __launch_bounds__(256) void k_stage(
    const float* __restrict__ x, const float* __restrict__ perb,
    u16* __restrict__ XS, int N)
{
    int tid = blockIdx.x * 256 + threadIdx.x;
    if (tid >= N * 32) return;
    int row = tid >> 5, seg = tid & 31;
    float4 xv = *(const float4*)(x + (size_t)row * 128 + seg * 4);
    float4 pv = *(const float4*)(perb + (size_t)row * 128 + seg * 4);
    u16* r = XS + (size_t)row * 256 + seg * 4;
    *(uint2*)r = make_uint2(pack2(xv.x, xv.y), pack2(xv.z, xv.w));
    *(uint2*)(r + 128) = make_uint2(pack2(xv.x + pv.x, xv.y + pv.y), pack2(xv.z + pv.z, xv.w + pv.w));
}

// ---------------- CSR build
__global__ void k_count(const int* __restrict__ row, int* __restrict__ cnt, int E) {
    int e = blockIdx.x * blockDim.x + threadIdx.x;
    if (e < E) atomicAdd(&cnt[row[e]], 1);
}

#define SCAN_CHUNK 512
__global__ __launch_bounds__(256) void k_bsum(const int* __restrict__ cnt, int* __restrict__ bsum, int N) {
    int t = threadIdx.x;
    int i0 = blockIdx.x * SCAN_CHUNK + t;
    int s = 0;
    if (i0 < N) s += cnt[i0];
    if (i0 + 256 < N) s += cnt[i0 + 256];
    __shared__ int red[256];
    red[t] = s; __syncthreads();
    for (int d = 128; d > 0; d >>= 1) { if (t < d) red[t] += red[t + d]; __syncthreads(); }
    if (t == 0) bsum[blockIdx.x] = red[0];
}

__global__ __launch_bounds__(256) void k_scan2(
    const int* __restrict__ cnt, const int* __restrict__ bsum,
    int* __restrict__ off, int N, int E)
{
    int b = blockIdx.x, t = threadIdx.x;
    __shared__ int red[256];
    __shared__ int sc[257];
    __shared__ int sbase;
    int ps = 0;
    for (int i = t; i < b; i += 256) ps += bsum[i];
    red[t] = ps; __syncthreads();
    for (int d = 128; d > 0; d >>= 1) { if (t < d) red[t] += red[t + d]; __syncthreads(); }
    if (t == 0) sbase = red[0];
    __syncthreads();
    int base = b * SCAN_CHUNK;
    int i0 = base + 2 * t, i1 = i0 + 1;
    int v0 = (i0 < N) ? cnt[i0] : 0;
    int v1 = (i1 < N) ? cnt[i1] : 0;
    int tsum = v0 + v1;
    sc[t] = tsum; __syncthreads();
    for (int d = 1; d < 256; d <<= 1) {
        int add = (t >= d) ? sc[t - d] : 0;
        __syncthreads();
        sc[t] += add;
        __syncthreads();
    }
    int excl = sbase + sc[t] - tsum;
    if (i0 < N) off[i0] = excl;
    if (i1 < N) off[i1] = excl + v0;
    if (b == 0 && t == 0) off[N] = E;
}

__global__ void k_scatter(const int* __restrict__ row, const int* __restrict__ col, const float* __restrict__ w,
                          const int* __restrict__ off, int* __restrict__ fill,
                          int* __restrict__ ccol, float* __restrict__ cw, int E) {
    int e = blockIdx.x * blockDim.x + threadIdx.x;
    if (e < E) {
        int r = row[e];
        int pos = off[r] + atomicAdd(&fill[r], 1);
        ccol[pos] = col[e];
        cw[pos] = w[e];
    }
}

// ---------------- k_agg: wave per node; 512B coalesced gather per edge
__global__ __launch_bounds__(256) void k_agg(
    const u16* __restrict__ XS, const int* __restrict__ off,
    const int* __restrict__ ccol, const float* __restrict__ cw,
    u16* __restrict__ AG, int N)
{
    int wave = threadIdx.x >> 6, lane = threadIdx.x & 63;
    int node = blockIdx.x * 4 + wave;
    if (node >= N) return;
    int o0 = off[node], o1 = off[node + 1];
    float a0 = 0.f, a1 = 0.f, a2 = 0.f, a3 = 0.f;
#pragma unroll 4
    for (int e = o0; e < o1; e++) {
        int c = ccol[e];
        float w = cw[e];
        uint2 v = ((const uint2*)(XS + (size_t)c * 256))[lane];
        a0 = fmaf(w, bf2f(v.x & 0xffffu), a0);
        a1 = fmaf(w, bf2f(v.x >> 16), a1);
        a2 = fmaf(w, bf2f(v.y & 0xffffu), a2);
        a3 = fmaf(w, bf2f(v.y >> 16), a3);
    }
    ((uint2*)(AG + (size_t)node * 256))[lane] = make_uint2(pack2(a0, a1), pack2(a2, a3));
}

// ---------------- k_hemb: W fragments staged in LDS (Won + Wc = 64 KB)
__global__ __launch_bounds__(256) void k_hemb(
    const u16* __restrict__ AG, const u16* __restrict__ Wfrag,
    const float* __restrict__ c1, const float* __restrict__ b_on,
    const float* __restrict__ x, const float* __restrict__ perb,
    u16* __restrict__ h1x, u16* __restrict__ h1y, float* __restrict__ out, int N)
{
    __shared__ uint4 sW[4096];   // [0..2047]=Won frags, [2048..4095]=Wc frags
    const int wave = threadIdx.x >> 6, lane = threadIdx.x & 63;
    const int m = lane & 15, q = lane >> 4;
    const int grow = blockIdx.x * 64 + wave * 16 + m;
    const int rc = grow < N ? grow : N - 1;
    const bool valid = grow < N;
    const u16* ar = AG + (size_t)rc * 256;
    const uint4* wfWon = (const uint4*)Wfrag;
    const uint4* wfWc  = (const uint4*)(Wfrag + 2 * 16384);
    short8 fa[4], fb[4];
#pragma unroll
    for (int ks = 0; ks < 4; ks++) {
        int c0 = ks * 32 + q * 8;
        F8 t;
        t.u4 = *(const uint4*)(ar + c0);       fa[ks] = t.s8;   // agg_x
        t.u4 = *(const uint4*)(ar + 128 + c0); fb[ks] = t.s8;   // agg_x2
    }
#pragma unroll
    for (int i = threadIdx.x; i < 2048; i += 256) {
        sW[i]        = wfWon[i];
        sW[i + 2048] = wfWc[i];
    }
    __syncthreads();
#pragma unroll 2
    for (int ct = 0; ct < 8; ct++) {
        floatx4 ax = {0.f, 0.f, 0.f, 0.f}, ay = {0.f, 0.f, 0.f, 0.f}, em = {0.f, 0.f, 0.f, 0.f};
#pragma unroll
        for (int ks = 0; ks < 4; ks++) {
            F8 wc, wo;
            wo.u4 = sW[(ct * 4 + ks) * 64 + lane];
            wc.u4 = sW[2048 + (ct * 4 + ks) * 64 + lane];
            ax = __builtin_amdgcn_mfma_f32_16x16x32_bf16(wc.s8, fa[ks], ax, 0, 0, 0);
            ay = __builtin_amdgcn_mfma_f32_16x16x32_bf16(wc.s8, fb[ks], ay, 0, 0, 0);
            em = __builtin_amdgcn_mfma_f32_16x16x32_bf16(wo.s8, fb[ks], em, 0, 0, 0);
        }
        if (valid) {
            int c0 = ct * 16 + q * 4;
            float4 cv = *(const float4*)(c1 + c0);
            float4 bo = *(const float4*)(b_on + c0);
            float4 xv = *(const float4*)(x + (size_t)grow * 128 + c0);
            float4 pv = *(const float4*)(perb + (size_t)grow * 128 + c0);
            *(uint2*)(h1x + (size_t)grow * 128 + c0) =
                make_uint2(pack2(ax[0] + cv.x, ax[1] + cv.y), pack2(ax[2] + cv.z, ax[3] + cv.w));
            *(uint2*)(h1y + (size_t)grow * 128 + c0) =
                make_uint2(pack2(ay[0] + cv.x, ay[1] + cv.y), pack2(ay[2] + cv.z, ay[3] + cv.w));
            float4 o;
            o.x = xv.x + pv.x + em[0] + bo.x;
            o.y = xv.y + pv.y + em[1] + bo.y;
            o.z = xv.z + pv.z + em[2] + bo.z;
            o.w = xv.w + pv.w + em[3] + bo.w;
            *(float4*)(out + (size_t)grow * 128 + c0) = o;
        }
    }
}

// ---------------- BN stats over bf16 h1
__global__ __launch_bounds__(256) void k_bnstats(
    const u32* __restrict__ h1x32, const u32* __restrict__ h1y32,
    float* __restrict__ sums, int N)
{
    int c2 = threadIdx.x & 63, g = threadIdx.x >> 6;
    int per = (N + gridDim.x - 1) / gridDim.x;
    int r0 = blockIdx.x * per, r1 = r0 + per;
    if (r1 > N) r1 = N;
    float s[8] = {0.f, 0.f, 0.f, 0.f, 0.f, 0.f, 0.f, 0.f};
    for (int r = r0 + g; r < r1; r += 4) {
        u32 vx = h1x32[(size_t)r * 64 + c2];
        float lo = bf2f(vx & 0xffffu), hi = bf2f(vx >> 16);
        s[0] += lo; s[1] = fmaf(lo, lo, s[1]); s[2] += hi; s[3] = fmaf(hi, hi, s[3]);
        u32 vy = h1y32[(size_t)r * 64 + c2];
        lo = bf2f(vy & 0xffffu); hi = bf2f(vy >> 16);
        s[4] += lo; s[5] = fmaf(lo, lo, s[5]); s[6] += hi; s[7] = fmaf(hi, hi, s[7]);
    }
    __shared__ float red[256][8];
#pragma unroll
    for (int k = 0; k < 8; k++) red[threadIdx.x][k] = s[k];
    __syncthreads();
    if (g == 0) {
        float v[8];
#pragma unroll
        for (int k = 0; k < 8; k++)
            v[k] = red[c2][k] + red[c2 + 64][k] + red[c2 + 128][k] + red[c2 + 192][k];
        int c0 = 2 * c2, c1i = c0 + 1;
        atomicAdd(&sums[c0], v[0]);        atomicAdd(&sums[128 + c0], v[1]);
        atomicAdd(&sums[c1i], v[2]);       atomicAdd(&sums[128 + c1i], v[3]);
        atomicAdd(&sums[256 + c0], v[4]);  atomicAdd(&sums[384 + c0], v[5]);
        atomicAdd(&sums[256 + c1i], v[6]); atomicAdd(&sums[384 + c1i], v[7]);
    }
}

__global__ __launch_bounds__(128) void k_bnfin(
    const float* __restrict__ sums, const float* __restrict__ g, const float* __restrict__ beta,
    float* __restrict__ bnp, int N)
{
    int d = threadIdx.x;
    float inv = 1.0f / (float)N;
    float mux = sums[d] * inv;
    float varx = sums[128 + d] * inv - mux * mux;
    float isx = rsqrtf(varx + 1e-5f);
    bnp[d]       = g[d] * isx;
    bnp[128 + d] = beta[d] - mux * g[d] * isx;
    float muy = sums[256 + d] * inv;
    float vary = sums[384 + d] * inv - muy * muy;
    float isy = rsqrtf(vary + 1e-5f);
    bnp[256 + d] = g[d] * isy;
    bnp[384 + d] = beta[d] - muy * g[d] * isy;
}

// ---------------- k_loss: W fragments staged in LDS (Wtg + W2 = 64 KB)
__device__ __forceinline__ short8 bn_frag(const u16* hrow, const float* sc, const float* sh,
                                          int c0, float slope) {
    uint4 h = *(const uint4*)(hrow + c0);
    float4 s0 = *(const float4*)(sc + c0), s1 = *(const float4*)(sc + c0 + 4);
    float4 t0 = *(const float4*)(sh + c0), t1 = *(const float4*)(sh + c0 + 4);
    float v[8];
    v[0] = fmaf(bf2f(h.x & 0xffffu), s0.x, t0.x);
    v[1] = fmaf(bf2f(h.x >> 16),     s0.y, t0.y);
    v[2] = fmaf(bf2f(h.y & 0xffffu), s0.z, t0.z);
    v[3] = fmaf(bf2f(h.y >> 16),     s0.w, t0.w);
    v[4] = fmaf(bf2f(h.z & 0xffffu), s1.x, t1.x);
    v[5] = fmaf(bf2f(h.z >> 16),     s1.y, t1.y);
    v[6] = fmaf(bf2f(h.w & 0xffffu), s1.z, t1.z);
    v[7] = fmaf(bf2f(h.w >> 16),     s1.w, t1.w);
#pragma unroll
    for (int j = 0; j < 8; j++) v[j] = v[j] > 0.f ? v[j] : slope * v[j];
    F8 r;
    r.u4 = make_uint4(pack2(v[0], v[1]), pack2(v[2], v[3]), pack2(v[4], v[5]), pack2(v[6], v[7]));
    return r.s8;
}

__global__ __launch_bounds__(256) void k_loss(
    const u16* __restrict__ h1x, const u16* __restrict__ h1y,
    const u16* __restrict__ AG, const u16* __restrict__ Wfrag,
    const float* __restrict__ bnp, const float* __restrict__ prelu_a,
    const float* __restrict__ b2, const float* __restrict__ b_tg,
    float* __restrict__ loss, int N)
{
    __shared__ uint4 sW[4096];   // [0..2047]=Wtg frags, [2048..4095]=W2 frags
    const int wave = threadIdx.x >> 6, lane = threadIdx.x & 63;
    const int m = lane & 15, q = lane >> 4;
    const int grow = blockIdx.x * 64 + wave * 16 + m;
    const int rc = grow < N ? grow : N - 1;
    const bool valid = grow < N;
    const float slope = prelu_a[0];
    const u16* hx = h1x + (size_t)rc * 128;
    const u16* hy = h1y + (size_t)rc * 128;
    const u16* ar = AG + (size_t)rc * 256;
    const uint4* wfTg = (const uint4*)(Wfrag + 1 * 16384);
    const uint4* wfW2 = (const uint4*)(Wfrag + 3 * 16384);
    short8 px8[4], py8[4], gx[4], gx2[4];
#pragma unroll
    for (int ks = 0; ks < 4; ks++) {
        int c0 = ks * 32 + q * 8;
        px8[ks] = bn_frag(hx, bnp, bnp + 128, c0, slope);
        py8[ks] = bn_frag(hy, bnp + 256, bnp + 384, c0, slope);
        F8 t;
        t.u4 = *(const uint4*)(ar + c0);       gx[ks] = t.s8;    // agg_x  -> target_y
        t.u4 = *(const uint4*)(ar + 128 + c0); gx2[ks] = t.s8;   // agg_x2 -> target_x
    }
#pragma unroll
    for (int i = threadIdx.x; i < 2048; i += 256) {
        sW[i]        = wfTg[i];
        sW[i + 2048] = wfW2[i];
    }
    __syncthreads();
    float pp = 0.f, pt = 0.f, tt = 0.f, qq = 0.f, qs = 0.f, ss = 0.f;
#pragma unroll 2
    for (int ct = 0; ct < 8; ct++) {
        floatx4 ax = {0.f, 0.f, 0.f, 0.f}, ay = {0.f, 0.f, 0.f, 0.f};
        floatx4 atx = {0.f, 0.f, 0.f, 0.f}, aty = {0.f, 0.f, 0.f, 0.f};
#pragma unroll
        for (int ks = 0; ks < 4; ks++) {
            F8 w2, wt;
            wt.u4 = sW[(ct * 4 + ks) * 64 + lane];
            w2.u4 = sW[2048 + (ct * 4 + ks) * 64 + lane];
            ax  = __builtin_amdgcn_mfma_f32_16x16x32_bf16(w2.s8, px8[ks], ax, 0, 0, 0);
            ay  = __builtin_amdgcn_mfma_f32_16x16x32_bf16(w2.s8, py8[ks], ay, 0, 0, 0);
            atx = __builtin_amdgcn_mfma_f32_16x16x32_bf16(wt.s8, gx2[ks], atx, 0, 0, 0);
            aty = __builtin_amdgcn_mfma_f32_16x16x32_bf16(wt.s8, gx[ks], aty, 0, 0, 0);
        }
        int c0 = ct * 16 + q * 4;
        float4 bv = *(const float4*)(b2 + c0);
        float4 tb = *(const float4*)(b_tg + c0);
#pragma unroll
        for (int j = 0; j < 4; j++) {
            float bvj = j == 0 ? bv.x : (j == 1 ? bv.y : (j == 2 ? bv.z : bv.w));
            float tbj = j == 0 ? tb.x : (j == 1 ? tb.y : (j == 2 ? tb.z : tb.w));
            float pxv = ax[j] + bvj, txv = atx[j] + tbj;
            float pyv = ay[j] + bvj, tyv = aty[j] + tbj;
            pp = fmaf(pxv, pxv, pp); pt = fmaf(pxv, txv, pt); tt = fmaf(txv, txv, tt);
            qq = fmaf(pyv, pyv, qq); qs = fmaf(pyv, tyv, qs); ss = fmaf(tyv, tyv, ss);
        }
    }
    pp += __shfl_xor(pp, 16); pt += __shfl_xor(pt, 16); tt += __shfl_xor(tt, 16);
    qq += __shfl_xor(qq, 16); qs += __shfl_xor(qs, 16); ss += __shfl_xor(ss, 16);
    pp += __shfl_xor(pp, 32); pt += __shfl_xor(pt, 32); tt += __shfl_xor(tt, 32);
    qq += __shfl_xor(qq, 32); qs += __shfl_xor(qs, 32); ss += __shfl_xor(ss, 32);
    float cx = pt / (fmaxf(sqrtf(pp), 1e-12f) * fmaxf(sqrtf(tt), 1e-12f));
    float cy = qs / (fmaxf(sqrtf(qq), 1e-12f) * fmaxf(sqrtf(ss), 1e-12f));
    float lsum = valid ? (4.f - 2.f * cx - 2.f * cy) : 0.f;
    lsum += __shfl_xor(lsum, 1); lsum += __shfl_xor(lsum, 2);
    lsum += __shfl_xor(lsum, 4); lsum += __shfl_xor(lsum, 8);
    if (lane == 0) atomicAdd(loss, lsum);
}

// ---------------- k_fin: loss scalar
__global__ void k_fin(const float* __restrict__ loss, float* __restrict__ out, int N) {
    if (threadIdx.x == 0) out[(size_t)N * 128] = loss[0] * (1.0f / (float)N);
}

extern "C" void kernel_launch(void* const* d_in, const int* in_sizes, int n_in,
                              void* d_out, int out_size, void* d_ws, size_t ws_size,
                              hipStream_t stream)
{
    const float* x    = (const float*)d_in[0];
    const float* perb = (const float*)d_in[1];
    const int*   erow = (const int*)d_in[2];
    const int*   ecol = (const int*)d_in[3];
    const float* ew   = (const float*)d_in[4];
    const float* Won  = (const float*)d_in[5];
    const float* bon  = (const float*)d_in[6];
    const float* Wtg  = (const float*)d_in[7];
    const float* btg  = (const float*)d_in[8];
    const float* W1   = (const float*)d_in[9];
    const float* b1   = (const float*)d_in[10];
    const float* bng  = (const float*)d_in[11];
    const float* bnb  = (const float*)d_in[12];
    const float* pra  = (const float*)d_in[13];
    const float* W2   = (const float*)d_in[14];
    const float* b2   = (const float*)d_in[15];
    float* out = (float*)d_out;

    const int N = in_sizes[0] / 128;
    const int E = in_sizes[2];

    char* ws = (char*)d_ws;
    u16* XS  = (u16*)ws;                                  // N*256 bf16
    u16* AG  = (u16*)(ws + (size_t)N * 512);              // N*256 bf16
    u16* h1x = (u16*)(ws + (size_t)N * 1024);             // N*128 bf16
    u16* h1y = (u16*)(ws + (size_t)N * 1024 + (size_t)N * 256);

    char* p = ws + (size_t)N * 1024 + (size_t)N * 512;
    const size_t szcnt = (((size_t)(N + 16) * 4) + 63) & ~(size_t)63;
    int* cnt  = (int*)p;      p += szcnt;
    int* fill = (int*)p;      p += szcnt;
    float* sums = (float*)p;  p += 2048;
    float* loss = (float*)p;  p += 64;
    size_t zero_bytes = (size_t)(p - (char*)cnt);
    int* off  = (int*)p;      p += szcnt;
    int* bsum = (int*)p;      p += 4096;
    int* ccol = (int*)p;      p += (((size_t)E * 4) + 63) & ~(size_t)63;
    float* cw = (float*)p;    p += (((size_t)E * 4) + 63) & ~(size_t)63;
    float* c1 = (float*)p;    p += 512;
    float* bnp = (float*)p;   p += 2048;
    float* Wc = (float*)p;    p += 128 * 128 * 4;
    u16* Wfrag = (u16*)p;     p += 4 * 16384 * 2;

    hipMemsetAsync(cnt, 0, zero_bytes, stream);

    const int nb64 = (N + 63) / 64;
    const int nbscan = (N + SCAN_CHUNK - 1) / SCAN_CHUNK;
    k_wc<<<65, 256, 0, stream>>>(Won, W1, bon, b1, Wc, c1);
    k_wfrag<<<4, 256, 0, stream>>>(Won, Wtg, Wc, W2, Wfrag);
    k_stage<<<(N * 32 + 255) / 256, 256, 0, stream>>>(x, perb, XS, N);
    k_count<<<(E + 255) / 256, 256, 0, stream>>>(erow, cnt, E);
    k_bsum<<<nbscan, 256, 0, stream>>>(cnt, bsum, N);
    k_scan2<<<nbscan, 256, 0, stream>>>(cnt, bsum, off, N, E);
    k_scatter<<<(E + 255) / 256, 256, 0, stream>>>(erow, ecol, ew, off, fill, ccol, cw, E);
    k_agg<<<(N + 3) / 4, 256, 0, stream>>>(XS, off, ccol, cw, AG, N);
    k_hemb<<<nb64, 256, 0, stream>>>(AG, Wfrag, c1, bon, x, perb, h1x, h1y, out, N);
    k_bnstats<<<128, 256, 0, stream>>>((const u32*)h1x, (const u32*)h1y, sums, N);
    k_bnfin<<<1, 128, 0, stream>>>(sums, bng, bnb, bnp, N);
    k_loss<<<nb64, 256, 0, stream>>>(h1x, h1y, AG, Wfrag, bnp, pra, b2, btg, loss, N);
    k_fin<<<1, 64, 0, stream>>>(loss, out, N);
}

// Round 6
// 381.409 us; speedup vs baseline: 2.0696x; 1.0844x over previous
//
#include <hip/hip_runtime.h>

typedef unsigned int u32;
typedef unsigned short u16;
typedef __attribute__((ext_vector_type(8))) short short8;
typedef __attribute__((ext_vector_type(4))) float floatx4;

union F8 { uint4 u4; short8 s8; };

__device__ __forceinline__ float bf2f(u32 lo16) { return __uint_as_float(lo16 << 16); }
__device__ __forceinline__ u16 f2bf(float f) {
    u32 u = __float_as_uint(f);
    return (u16)((u + 0x7FFFu + ((u >> 16) & 1u)) >> 16);
}
__device__ __forceinline__ u32 pack2(float a, float b) {
    return (u32)f2bf(a) | ((u32)f2bf(b) << 16);
}

// ---------------- k_front: blocks [0,64)=Wc, 64=c1, [65,65+NS)=stage, rest=count
__global__ __launch_bounds__(256) void k_front(
    const float* __restrict__ x, const float* __restrict__ perb,
    const int* __restrict__ erow,
    const float* __restrict__ Won, const float* __restrict__ W1,
    const float* __restrict__ b_on, const float* __restrict__ b1,
    u16* __restrict__ XS, int* __restrict__ cnt,
    float* __restrict__ Wc, float* __restrict__ c1,
    int N, int E, int NS)
{
    int b = blockIdx.x, t = threadIdx.x;
    if (b < 64) {
        int tid = b * 256 + t;
        int i = tid >> 7, j = tid & 127;
        float s = 0.f;
        for (int k = 0; k < 128; k++) s = fmaf(Won[i * 128 + k], W1[k * 128 + j], s);
        Wc[tid] = s;
    } else if (b == 64) {
        if (t < 128) {
            float s = b1[t];
            for (int k = 0; k < 128; k++) s = fmaf(b_on[k], W1[k * 128 + t], s);
            c1[t] = s;
        }
    } else if (b < 65 + NS) {
        int tid = (b - 65) * 256 + t;
        if (tid < N * 32) {
            int row = tid >> 5, seg = tid & 31;
            float4 xv = *(const float4*)(x + (size_t)row * 128 + seg * 4);
            float4 pv = *(const float4*)(perb + (size_t)row * 128 + seg * 4);
            u16* r = XS + (size_t)row * 256 + seg * 4;
            *(uint2*)r = make_uint2(pack2(xv.x, xv.y), pack2(xv.z, xv.w));
            *(uint2*)(r + 128) = make_uint2(pack2(xv.x + pv.x, xv.y + pv.y), pack2(xv.z + pv.z, xv.w + pv.w));
        }
    } else {
        int e = (b - 65 - NS) * 256 + t;
        if (e < E) atomicAdd(&cnt[erow[e]], 1);
    }
}

#define SCAN_CHUNK 512
// ---------------- k_mid: blocks [0,4)=wfrag, rest=bsum
__global__ __launch_bounds__(256) void k_mid(
    const float* __restrict__ Won, const float* __restrict__ Wtg,
    const float* __restrict__ Wc, const float* __restrict__ W2,
    u16* __restrict__ Wfrag,
    const int* __restrict__ cnt, int* __restrict__ bsum, int N, int nbscan)
{
    __shared__ int red[256];
    int b = blockIdx.x, t = threadIdx.x;
    if (b < 4) {
        int mat = b;
        const float* W = mat == 0 ? Won : (mat == 1 ? Wtg : (mat == 2 ? Wc : W2));
        uint4* out = (uint4*)(Wfrag + (size_t)mat * 16384);
        for (int s = t; s < 2048; s += 256) {
            int lane = s & 63;
            int n = ((s >> 8) << 4) + (lane & 15);
            int k0 = ((s >> 6) & 3) * 32 + (lane >> 4) * 8;
            u32 p[4];
#pragma unroll
            for (int jj = 0; jj < 4; jj++) {
                float a = W[(size_t)(k0 + 2 * jj) * 128 + n];
                float bb = W[(size_t)(k0 + 2 * jj + 1) * 128 + n];
                p[jj] = pack2(a, bb);
            }
            out[s] = make_uint4(p[0], p[1], p[2], p[3]);
        }
    } else {
        int bb = b - 4;
        if (bb >= nbscan) return;
        int i0 = bb * SCAN_CHUNK + t;
        int s = 0;
        if (i0 < N) s += cnt[i0];
        if (i0 + 256 < N) s += cnt[i0 + 256];
        red[t] = s; __syncthreads();
        for (int d = 128; d > 0; d >>= 1) { if (t < d) red[t] += red[t + d]; __syncthreads(); }
        if (t == 0) bsum[bb] = red[0];
    }
}

__global__ __launch_bounds__(256) void k_scan2(
    const int* __restrict__ cnt, const int* __restrict__ bsum,
    int* __restrict__ off, int N, int E)
{
    int b = blockIdx.x, t = threadIdx.x;
    __shared__ int red[256];
    __shared__ int sc[257];
    __shared__ int sbase;
    int ps = 0;
    for (int i = t; i < b; i += 256) ps += bsum[i];
    red[t] = ps; __syncthreads();
    for (int d = 128; d > 0; d >>= 1) { if (t < d) red[t] += red[t + d]; __syncthreads(); }
    if (t == 0) sbase = red[0];
    __syncthreads();
    int base = b * SCAN_CHUNK;
    int i0 = base + 2 * t, i1 = i0 + 1;
    int v0 = (i0 < N) ? cnt[i0] : 0;
    int v1 = (i1 < N) ? cnt[i1] : 0;
    int tsum = v0 + v1;
    sc[t] = tsum; __syncthreads();
    for (int d = 1; d < 256; d <<= 1) {
        int add = (t >= d) ? sc[t - d] : 0;
        __syncthreads();
        sc[t] += add;
        __syncthreads();
    }
    int excl = sbase + sc[t] - tsum;
    if (i0 < N) off[i0] = excl;
    if (i1 < N) off[i1] = excl + v0;
    if (b == 0 && t == 0) off[N] = E;
}

// ---------------- k_scatter: packed (col,w) single 8B store; cnt countdown
__global__ void k_scatter(const int* __restrict__ row, const int* __restrict__ col, const float* __restrict__ w,
                          const int* __restrict__ off, int* __restrict__ cnt,
                          uint2* __restrict__ cpack, int E) {
    int e = blockIdx.x * blockDim.x + threadIdx.x;
    if (e < E) {
        int r = row[e];
        int pos = off[r] + atomicSub(&cnt[r], 1) - 1;
        cpack[pos] = make_uint2((u32)col[e], __float_as_uint(w[e]));
    }
}

// ---------------- k_agg: wave per node; 512B coalesced gather per edge
__global__ __launch_bounds__(256) void k_agg(
    const u16* __restrict__ XS, const int* __restrict__ off,
    const uint2* __restrict__ cpack, u16* __restrict__ AG, int N)
{
    int wave = threadIdx.x >> 6, lane = threadIdx.x & 63;
    int node = blockIdx.x * 4 + wave;
    if (node >= N) return;
    int o0 = off[node], o1 = off[node + 1];
    float a0 = 0.f, a1 = 0.f, a2 = 0.f, a3 = 0.f;
#pragma unroll 4
    for (int e = o0; e < o1; e++) {
        uint2 rec = cpack[e];
        int c = (int)rec.x;
        float w = __uint_as_float(rec.y);
        uint2 v = ((const uint2*)(XS + (size_t)c * 256))[lane];
        a0 = fmaf(w, bf2f(v.x & 0xffffu), a0);
        a1 = fmaf(w, bf2f(v.x >> 16), a1);
        a2 = fmaf(w, bf2f(v.y & 0xffffu), a2);
        a3 = fmaf(w, bf2f(v.y >> 16), a3);
    }
    ((uint2*)(AG + (size_t)node * 256))[lane] = make_uint2(pack2(a0, a1), pack2(a2, a3));
}

// ---------------- k_hemb: W fragments staged in LDS (Won + Wc = 64 KB)
__global__ __launch_bounds__(256) void k_hemb(
    const u16* __restrict__ AG, const u16* __restrict__ Wfrag,
    const float* __restrict__ c1, const float* __restrict__ b_on,
    const float* __restrict__ x, const float* __restrict__ perb,
    u16* __restrict__ h1x, u16* __restrict__ h1y, float* __restrict__ out, int N)
{
    __shared__ uint4 sW[4096];
    const int wave = threadIdx.x >> 6, lane = threadIdx.x & 63;
    const int m = lane & 15, q = lane >> 4;
    const int grow = blockIdx.x * 64 + wave * 16 + m;
    const int rc = grow < N ? grow : N - 1;
    const bool valid = grow < N;
    const u16* ar = AG + (size_t)rc * 256;
    const uint4* wfWon = (const uint4*)Wfrag;
    const uint4* wfWc  = (const uint4*)(Wfrag + 2 * 16384);
    short8 fa[4], fb[4];
#pragma unroll
    for (int ks = 0; ks < 4; ks++) {
        int c0 = ks * 32 + q * 8;
        F8 t;
        t.u4 = *(const uint4*)(ar + c0);       fa[ks] = t.s8;
        t.u4 = *(const uint4*)(ar + 128 + c0); fb[ks] = t.s8;
    }
#pragma unroll
    for (int i = threadIdx.x; i < 2048; i += 256) {
        sW[i]        = wfWon[i];
        sW[i + 2048] = wfWc[i];
    }
    __syncthreads();
#pragma unroll 2
    for (int ct = 0; ct < 8; ct++) {
        floatx4 ax = {0.f, 0.f, 0.f, 0.f}, ay = {0.f, 0.f, 0.f, 0.f}, em = {0.f, 0.f, 0.f, 0.f};
#pragma unroll
        for (int ks = 0; ks < 4; ks++) {
            F8 wc, wo;
            wo.u4 = sW[(ct * 4 + ks) * 64 + lane];
            wc.u4 = sW[2048 + (ct * 4 + ks) * 64 + lane];
            ax = __builtin_amdgcn_mfma_f32_16x16x32_bf16(wc.s8, fa[ks], ax, 0, 0, 0);
            ay = __builtin_amdgcn_mfma_f32_16x16x32_bf16(wc.s8, fb[ks], ay, 0, 0, 0);
            em = __builtin_amdgcn_mfma_f32_16x16x32_bf16(wo.s8, fb[ks], em, 0, 0, 0);
        }
        if (valid) {
            int c0 = ct * 16 + q * 4;
            float4 cv = *(const float4*)(c1 + c0);
            float4 bo = *(const float4*)(b_on + c0);
            float4 xv = *(const float4*)(x + (size_t)grow * 128 + c0);
            float4 pv = *(const float4*)(perb + (size_t)grow * 128 + c0);
            *(uint2*)(h1x + (size_t)grow * 128 + c0) =
                make_uint2(pack2(ax[0] + cv.x, ax[1] + cv.y), pack2(ax[2] + cv.z, ax[3] + cv.w));
            *(uint2*)(h1y + (size_t)grow * 128 + c0) =
                make_uint2(pack2(ay[0] + cv.x, ay[1] + cv.y), pack2(ay[2] + cv.z, ay[3] + cv.w));
            float4 o;
            o.x = xv.x + pv.x + em[0] + bo.x;
            o.y = xv.y + pv.y + em[1] + bo.y;
            o.z = xv.z + pv.z + em[2] + bo.z;
            o.w = xv.w + pv.w + em[3] + bo.w;
            *(float4*)(out + (size_t)grow * 128 + c0) = o;
        }
    }
}

// ---------------- k_bnstats (+ fused bnfin via ticket)
__global__ __launch_bounds__(256) void k_bnstats(
    const u32* __restrict__ h1x32, const u32* __restrict__ h1y32,
    float* __restrict__ sums, int* __restrict__ tick,
    const float* __restrict__ g, const float* __restrict__ beta,
    float* __restrict__ bnp, int N)
{
    int c2 = threadIdx.x & 63, gg = threadIdx.x >> 6;
    int per = (N + gridDim.x - 1) / gridDim.x;
    int r0 = blockIdx.x * per, r1 = r0 + per;
    if (r1 > N) r1 = N;
    float s[8] = {0.f, 0.f, 0.f, 0.f, 0.f, 0.f, 0.f, 0.f};
    for (int r = r0 + gg; r < r1; r += 4) {
        u32 vx = h1x32[(size_t)r * 64 + c2];
        float lo = bf2f(vx & 0xffffu), hi = bf2f(vx >> 16);
        s[0] += lo; s[1] = fmaf(lo, lo, s[1]); s[2] += hi; s[3] = fmaf(hi, hi, s[3]);
        u32 vy = h1y32[(size_t)r * 64 + c2];
        lo = bf2f(vy & 0xffffu); hi = bf2f(vy >> 16);
        s[4] += lo; s[5] = fmaf(lo, lo, s[5]); s[6] += hi; s[7] = fmaf(hi, hi, s[7]);
    }
    __shared__ float red[256][8];
    __shared__ int lastflag;
#pragma unroll
    for (int k = 0; k < 8; k++) red[threadIdx.x][k] = s[k];
    __syncthreads();
    if (gg == 0) {
        float v[8];
#pragma unroll
        for (int k = 0; k < 8; k++)
            v[k] = red[c2][k] + red[c2 + 64][k] + red[c2 + 128][k] + red[c2 + 192][k];
        int c0 = 2 * c2, c1i = c0 + 1;
        atomicAdd(&sums[c0], v[0]);        atomicAdd(&sums[128 + c0], v[1]);
        atomicAdd(&sums[c1i], v[2]);       atomicAdd(&sums[128 + c1i], v[3]);
        atomicAdd(&sums[256 + c0], v[4]);  atomicAdd(&sums[384 + c0], v[5]);
        atomicAdd(&sums[256 + c1i], v[6]); atomicAdd(&sums[384 + c1i], v[7]);
    }
    __syncthreads();
    if (threadIdx.x == 0) {
        __threadfence();
        int old = atomicAdd(tick, 1);
        lastflag = (old == (int)gridDim.x - 1) ? 1 : 0;
    }
    __syncthreads();
    if (lastflag && threadIdx.x < 128) {
        int d = threadIdx.x;
        float inv = 1.0f / (float)N;
        float s0 = atomicAdd(&sums[d], 0.f);
        float s1 = atomicAdd(&sums[128 + d], 0.f);
        float s2 = atomicAdd(&sums[256 + d], 0.f);
        float s3 = atomicAdd(&sums[384 + d], 0.f);
        float mux = s0 * inv;
        float varx = s1 * inv - mux * mux;
        float isx = rsqrtf(varx + 1e-5f);
        bnp[d]       = g[d] * isx;
        bnp[128 + d] = beta[d] - mux * g[d] * isx;
        float muy = s2 * inv;
        float vary = s3 * inv - muy * muy;
        float isy = rsqrtf(vary + 1e-5f);
        bnp[256 + d] = g[d] * isy;
        bnp[384 + d] = beta[d] - muy * g[d] * isy;
    }
}

// ---------------- k_loss (+ fused finalize via ticket)
__device__ __forceinline__ short8 bn_frag(const u16* hrow, const float* sc, const float* sh,
                                          int c0, float slope) {
    uint4 h = *(const uint4*)(hrow + c0);
    float4 s0 = *(const float4*)(sc + c0), s1 = *(const float4*)(sc + c0 + 4);
    float4 t0 = *(const float4*)(sh + c0), t1 = *(const float4*)(sh + c0 + 4);
    float v[8];
    v[0] = fmaf(bf2f(h.x & 0xffffu), s0.x, t0.x);
    v[1] = fmaf(bf2f(h.x >> 16),     s0.y, t0.y);
    v[2] = fmaf(bf2f(h.y & 0xffffu), s0.z, t0.z);
    v[3] = fmaf(bf2f(h.y >> 16),     s0.w, t0.w);
    v[4] = fmaf(bf2f(h.z & 0xffffu), s1.x, t1.x);
    v[5] = fmaf(bf2f(h.z >> 16),     s1.y, t1.y);
    v[6] = fmaf(bf2f(h.w & 0xffffu), s1.z, t1.z);
    v[7] = fmaf(bf2f(h.w >> 16),     s1.w, t1.w);
#pragma unroll
    for (int j = 0; j < 8; j++) v[j] = v[j] > 0.f ? v[j] : slope * v[j];
    F8 r;
    r.u4 = make_uint4(pack2(v[0], v[1]), pack2(v[2], v[3]), pack2(v[4], v[5]), pack2(v[6], v[7]));
    return r.s8;
}

__global__ __launch_bounds__(256) void k_loss(
    const u16* __restrict__ h1x, const u16* __restrict__ h1y,
    const u16* __restrict__ AG, const u16* __restrict__ Wfrag,
    const float* __restrict__ bnp, const float* __restrict__ prelu_a,
    const float* __restrict__ b2, const float* __restrict__ b_tg,
    float* __restrict__ loss, int* __restrict__ tick, float* __restrict__ out, int N)
{
    __shared__ uint4 sW[4096];
    __shared__ float lred[4];
    __shared__ int lastflag;
    const int wave = threadIdx.x >> 6, lane = threadIdx.x & 63;
    const int m = lane & 15, q = lane >> 4;
    const int grow = blockIdx.x * 64 + wave * 16 + m;
    const int rc = grow < N ? grow : N - 1;
    const bool valid = grow < N;
    const float slope = prelu_a[0];
    const u16* hx = h1x + (size_t)rc * 128;
    const u16* hy = h1y + (size_t)rc * 128;
    const u16* ar = AG + (size_t)rc * 256;
    const uint4* wfTg = (const uint4*)(Wfrag + 1 * 16384);
    const uint4* wfW2 = (const uint4*)(Wfrag + 3 * 16384);
    short8 px8[4], py8[4], gx[4], gx2[4];
#pragma unroll
    for (int ks = 0; ks < 4; ks++) {
        int c0 = ks * 32 + q * 8;
        px8[ks] = bn_frag(hx, bnp, bnp + 128, c0, slope);
        py8[ks] = bn_frag(hy, bnp + 256, bnp + 384, c0, slope);
        F8 t;
        t.u4 = *(const uint4*)(ar + c0);       gx[ks] = t.s8;
        t.u4 = *(const uint4*)(ar + 128 + c0); gx2[ks] = t.s8;
    }
#pragma unroll
    for (int i = threadIdx.x; i < 2048; i += 256) {
        sW[i]        = wfTg[i];
        sW[i + 2048] = wfW2[i];
    }
    __syncthreads();
    float pp = 0.f, pt = 0.f, tt = 0.f, qq = 0.f, qs = 0.f, ss = 0.f;
#pragma unroll 2
    for (int ct = 0; ct < 8; ct++) {
        floatx4 ax = {0.f, 0.f, 0.f, 0.f}, ay = {0.f, 0.f, 0.f, 0.f};
        floatx4 atx = {0.f, 0.f, 0.f, 0.f}, aty = {0.f, 0.f, 0.f, 0.f};
#pragma unroll
        for (int ks = 0; ks < 4; ks++) {
            F8 w2, wt;
            wt.u4 = sW[(ct * 4 + ks) * 64 + lane];
            w2.u4 = sW[2048 + (ct * 4 + ks) * 64 + lane];
            ax  = __builtin_amdgcn_mfma_f32_16x16x32_bf16(w2.s8, px8[ks], ax, 0, 0, 0);
            ay  = __builtin_amdgcn_mfma_f32_16x16x32_bf16(w2.s8, py8[ks], ay, 0, 0, 0);
            atx = __builtin_amdgcn_mfma_f32_16x16x32_bf16(wt.s8, gx2[ks], atx, 0, 0, 0);
            aty = __builtin_amdgcn_mfma_f32_16x16x32_bf16(wt.s8, gx[ks], aty, 0, 0, 0);
        }
        int c0 = ct * 16 + q * 4;
        float4 bv = *(const float4*)(b2 + c0);
        float4 tb = *(const float4*)(b_tg + c0);
#pragma unroll
        for (int j = 0; j < 4; j++) {
            float bvj = j == 0 ? bv.x : (j == 1 ? bv.y : (j == 2 ? bv.z : bv.w));
            float tbj = j == 0 ? tb.x : (j == 1 ? tb.y : (j == 2 ? tb.z : tb.w));
            float pxv = ax[j] + bvj, txv = atx[j] + tbj;
            float pyv = ay[j] + bvj, tyv = aty[j] + tbj;
            pp = fmaf(pxv, pxv, pp); pt = fmaf(pxv, txv, pt); tt = fmaf(txv, txv, tt);
            qq = fmaf(pyv, pyv, qq); qs = fmaf(pyv, tyv, qs); ss = fmaf(tyv, tyv, ss);
        }
    }
    pp += __shfl_xor(pp, 16); pt += __shfl_xor(pt, 16); tt += __shfl_xor(tt, 16);
    qq += __shfl_xor(qq, 16); qs += __shfl_xor(qs, 16); ss += __shfl_xor(ss, 16);
    pp += __shfl_xor(pp, 32); pt += __shfl_xor(pt, 32); tt += __shfl_xor(tt, 32);
    qq += __shfl_xor(qq, 32); qs += __shfl_xor(qs, 32); ss += __shfl_xor(ss, 32);
    float cx = pt / (fmaxf(sqrtf(pp), 1e-12f) * fmaxf(sqrtf(tt), 1e-12f));
    float cy = qs / (fmaxf(sqrtf(qq), 1e-12f) * fmaxf(sqrtf(ss), 1e-12f));
    float lsum = valid ? (4.f - 2.f * cx - 2.f * cy) : 0.f;
    lsum += __shfl_xor(lsum, 1); lsum += __shfl_xor(lsum, 2);
    lsum += __shfl_xor(lsum, 4); lsum += __shfl_xor(lsum, 8);
    if (lane == 0) lred[wave] = lsum;
    __syncthreads();
    if (threadIdx.x == 0) {
        atomicAdd(loss, lred[0] + lred[1] + lred[2] + lred[3]);
        __threadfence();
        int old = atomicAdd(tick, 1);
        lastflag = (old == (int)gridDim.x - 1) ? 1 : 0;
        if (lastflag) {
            float v = atomicAdd(loss, 0.f);
            out[(size_t)N * 128] = v * (1.0f / (float)N);
        }
    }
}

extern "C" void kernel_launch(void* const* d_in, const int* in_sizes, int n_in,
                              void* d_out, int out_size, void* d_ws, size_t ws_size,
                              hipStream_t stream)
{
    const float* x    = (const float*)d_in[0];
    const float* perb = (const float*)d_in[1];
    const int*   erow = (const int*)d_in[2];
    const int*   ecol = (const int*)d_in[3];
    const float* ew   = (const float*)d_in[4];
    const float* Won  = (const float*)d_in[5];
    const float* bon  = (const float*)d_in[6];
    const float* Wtg  = (const float*)d_in[7];
    const float* btg  = (const float*)d_in[8];
    const float* W1   = (const float*)d_in[9];
    const float* b1   = (const float*)d_in[10];
    const float* bng  = (const float*)d_in[11];
    const float* bnb  = (const float*)d_in[12];
    const float* pra  = (const float*)d_in[13];
    const float* W2   = (const float*)d_in[14];
    const float* b2   = (const float*)d_in[15];
    float* out = (float*)d_out;

    const int N = in_sizes[0] / 128;
    const int E = in_sizes[2];

    char* ws = (char*)d_ws;
    u16* XS  = (u16*)ws;
    u16* AG  = (u16*)(ws + (size_t)N * 512);
    u16* h1x = (u16*)(ws + (size_t)N * 1024);
    u16* h1y = (u16*)(ws + (size_t)N * 1024 + (size_t)N * 256);

    char* p = ws + (size_t)N * 1024 + (size_t)N * 512;
    const size_t szcnt = (((size_t)(N + 16) * 4) + 63) & ~(size_t)63;
    int* cnt  = (int*)p;      p += szcnt;
    float* sums = (float*)p;  p += 2048;
    float* loss = (float*)p;  p += 64;
    int* ticks = (int*)p;     p += 64;
    size_t zero_bytes = (size_t)(p - (char*)cnt);
    int* off  = (int*)p;      p += szcnt;
    int* bsum = (int*)p;      p += 4096;
    uint2* cpack = (uint2*)p; p += (((size_t)E * 8) + 63) & ~(size_t)63;
    float* c1 = (float*)p;    p += 512;
    float* bnp = (float*)p;   p += 2048;
    float* Wc = (float*)p;    p += 128 * 128 * 4;
    u16* Wfrag = (u16*)p;     p += 4 * 16384 * 2;

    hipMemsetAsync(cnt, 0, zero_bytes, stream);

    const int nb64 = (N + 63) / 64;
    const int nbscan = (N + SCAN_CHUNK - 1) / SCAN_CHUNK;
    const int NS = (N * 32 + 255) / 256;
    const int NC = (E + 255) / 256;

    k_front<<<65 + NS + NC, 256, 0, stream>>>(x, perb, erow, Won, W1, bon, b1,
                                              XS, cnt, Wc, c1, N, E, NS);
    k_mid<<<4 + nbscan, 256, 0, stream>>>(Won, Wtg, Wc, W2, Wfrag, cnt, bsum, N, nbscan);
    k_scan2<<<nbscan, 256, 0, stream>>>(cnt, bsum, off, N, E);
    k_scatter<<<NC, 256, 0, stream>>>(erow, ecol, ew, off, cnt, cpack, E);
    k_agg<<<(N + 3) / 4, 256, 0, stream>>>(XS, off, cpack, AG, N);
    k_hemb<<<nb64, 256, 0, stream>>>(AG, Wfrag, c1, bon, x, perb, h1x, h1y, out, N);
    k_bnstats<<<128, 256, 0, stream>>>((const u32*)h1x, (const u32*)h1y, sums, ticks, bng, bnb, bnp, N);
    k_loss<<<nb64, 256, 0, stream>>>(h1x, h1y, AG, Wfrag, bnp, pra, b2, btg, loss, ticks + 1, out, N);
}